// Round 1
// baseline (1892.815 us; speedup 1.0000x reference)
//
#include <hip/hip_runtime.h>

#define BB 8
#define CIN0 512
#define SS 784            // 28*28
#define NHEADS 8
#define DHEAD 32

// Out[b][o][p] = scale * (sum_c W[o][c] * X[b][c][p] + bias[o])
template<int CIN>
__global__ __launch_bounds__(256) void proj_gemm(const float* __restrict__ X,
                                                 const float* __restrict__ W,
                                                 const float* __restrict__ bias,
                                                 float* __restrict__ Out,
                                                 int Cout, float scale) {
    __shared__ __align__(16) float Ws[16][68];   // [c_local][o_local], pad 68 keeps 16B align + spreads banks
    __shared__ __align__(16) float Xs[16][64];   // [c_local][p_local]
    const int tid = threadIdx.x;
    const int tx = tid & 15;          // p group
    const int ty = tid >> 4;          // o group
    const int p0 = blockIdx.x * 64;
    const int o0 = blockIdx.y * 64;
    const int b  = blockIdx.z;

    float acc[4][4] = {};
    const float* Xb = X + (size_t)b * CIN * SS;

    for (int c0 = 0; c0 < CIN; c0 += 16) {
        __syncthreads();
        // W tile: rows o0..o0+63, cols c0..c0+15 -> Ws[c][o]
        #pragma unroll
        for (int i = 0; i < 4; ++i) {
            int idx = tid + 256 * i;          // 0..1023
            int row = idx >> 4;               // 0..63 (o)
            int col = idx & 15;               // 0..15 (c)
            Ws[col][row] = W[(size_t)(o0 + row) * CIN + c0 + col];
        }
        // X tile: rows c0..c0+15, cols p0..p0+63
        #pragma unroll
        for (int i = 0; i < 4; ++i) {
            int idx = tid + 256 * i;
            int row = idx >> 6;               // 0..15 (c)
            int col = idx & 63;               // 0..63 (p)
            int p = p0 + col;
            Xs[row][col] = (p < SS) ? Xb[(size_t)(c0 + row) * SS + p] : 0.0f;
        }
        __syncthreads();
        #pragma unroll
        for (int kk = 0; kk < 16; ++kk) {
            float4 a4 = *(const float4*)&Ws[kk][ty * 4];
            float4 x4 = *(const float4*)&Xs[kk][tx * 4];
            acc[0][0] += a4.x * x4.x; acc[0][1] += a4.x * x4.y; acc[0][2] += a4.x * x4.z; acc[0][3] += a4.x * x4.w;
            acc[1][0] += a4.y * x4.x; acc[1][1] += a4.y * x4.y; acc[1][2] += a4.y * x4.z; acc[1][3] += a4.y * x4.w;
            acc[2][0] += a4.z * x4.x; acc[2][1] += a4.z * x4.y; acc[2][2] += a4.z * x4.z; acc[2][3] += a4.z * x4.w;
            acc[3][0] += a4.w * x4.x; acc[3][1] += a4.w * x4.y; acc[3][2] += a4.w * x4.z; acc[3][3] += a4.w * x4.w;
        }
    }

    #pragma unroll
    for (int i = 0; i < 4; ++i) {
        int o = o0 + ty * 4 + i;
        float bv = bias[o];
        #pragma unroll
        for (int j = 0; j < 4; ++j) {
            int p = p0 + tx * 4 + j;
            if (p < SS)
                Out[((size_t)b * Cout + o) * SS + p] = (acc[i][j] + bv) * scale;
        }
    }
}

// Fused: logits (QK^T per head) -> softmax over HEADS -> PV, with the reference's
// raw (s,d)->(e,p) reshape folded into the attn2 write.
// One wave per (b,s); lane l + reg r owns channel c = r*64 + l (head n=c/32, d=c%32).
__global__ __launch_bounds__(512) void attn_fused(const float* __restrict__ q,
                                                  const float* __restrict__ kv,
                                                  float* __restrict__ attn2) {
    __shared__ __align__(16) float ks[256][17];
    __shared__ __align__(16) float vs[256][17];
    const int tid  = threadIdx.x;
    const int lane = tid & 63;
    const int wave = tid >> 6;                 // 0..7
    const int b    = blockIdx.x / 98;
    const int s    = (blockIdx.x % 98) * 8 + wave;

    const float* qb = q  + (size_t)b * 256 * SS;
    const float* kb = kv + (size_t)b * 512 * SS;        // k: channels 0..255
    const float* vb = kb + (size_t)256 * SS;            // v: channels 256..511

    float qr[4], acc[4];
    #pragma unroll
    for (int r = 0; r < 4; ++r) {
        qr[r]  = qb[(size_t)(r * 64 + lane) * SS + s];  // q already scaled by 1/sqrt(32)
        acc[r] = 0.0f;
    }

    const int lcol = tid & 15;     // t offset
    const int lrow = tid >> 4;     // 0..31 row base

    for (int t0 = 0; t0 < SS; t0 += 16) {
        __syncthreads();
        #pragma unroll
        for (int i = 0; i < 8; ++i) {
            int row = lrow + 32 * i;
            ks[row][lcol] = kb[(size_t)row * SS + t0 + lcol];
            vs[row][lcol] = vb[(size_t)row * SS + t0 + lcol];
        }
        __syncthreads();
        #pragma unroll 4
        for (int tt = 0; tt < 16; ++tt) {
            float l[4];
            #pragma unroll
            for (int r = 0; r < 4; ++r)
                l[r] = qr[r] * ks[r * 64 + lane][tt];
            // segmented sum over 32-lane groups (= one head's d=0..31)
            #pragma unroll
            for (int d = 1; d < 32; d <<= 1) {
                #pragma unroll
                for (int r = 0; r < 4; ++r)
                    l[r] += __shfl_xor(l[r], d, 64);
            }
            // softmax over the 8 heads: lanes<32 hold heads {0,2,4,6}, lanes>=32 hold {1,3,5,7}
            float m = fmaxf(fmaxf(l[0], l[1]), fmaxf(l[2], l[3]));
            m = fmaxf(m, __shfl_xor(m, 32, 64));
            float e[4];
            float dsum = 0.0f;
            #pragma unroll
            for (int r = 0; r < 4; ++r) { e[r] = __expf(l[r] - m); dsum += e[r]; }
            dsum += __shfl_xor(dsum, 32, 64);
            float inv = 1.0f / dsum;
            #pragma unroll
            for (int r = 0; r < 4; ++r)
                acc[r] += (e[r] * inv) * vs[r * 64 + lane][tt];
        }
    }

    // reference reshape quirk: within head n, flat f = s*32 + d reinterpreted as (e,p)=(f/784, f%784),
    // output channel c2 = n*32 + e
    #pragma unroll
    for (int r = 0; r < 4; ++r) {
        int c  = r * 64 + lane;
        int n  = c >> 5;
        int d  = c & 31;
        int f  = s * 32 + d;
        int e  = f / SS;
        int p  = f % SS;
        attn2[((size_t)b * 256 + n * 32 + e) * SS + p] = acc[r];
    }
}

extern "C" void kernel_launch(void* const* d_in, const int* in_sizes, int n_in,
                              void* d_out, int out_size, void* d_ws, size_t ws_size,
                              hipStream_t stream) {
    const float* inputs    = (const float*)d_in[0];
    const float* inputs_st = (const float*)d_in[1];
    const float* Wq        = (const float*)d_in[2];
    const float* bq        = (const float*)d_in[3];
    const float* Wkv       = (const float*)d_in[4];
    const float* bkv       = (const float*)d_in[5];
    const float* Wo        = (const float*)d_in[6];
    const float* bo        = (const float*)d_in[7];
    float* out = (float*)d_out;

    float* q     = (float*)d_ws;                       // 8*256*784
    float* kvb   = q   + (size_t)BB * 256 * SS;        // 8*512*784
    float* attn2 = kvb + (size_t)BB * 512 * SS;        // 8*256*784
    // total ws use: 25.7 MB

    dim3 blk(256);
    // Q projection (scale = 1/sqrt(32) applied to conv+bias, per reference)
    proj_gemm<512><<<dim3(13, 4, BB), blk, 0, stream>>>(inputs, Wq, bq, q, 256, 0.17677669529663687f);
    // KV projection
    proj_gemm<512><<<dim3(13, 8, BB), blk, 0, stream>>>(inputs_st, Wkv, bkv, kvb, 512, 1.0f);
    // fused attention (head-axis softmax)
    attn_fused<<<dim3(784), dim3(512), 0, stream>>>(q, kvb, attn2);
    // output projection
    proj_gemm<256><<<dim3(13, 8, BB), blk, 0, stream>>>(attn2, Wo, bo, out, 512, 1.0f);
}

// Round 2
// 310.763 us; speedup vs baseline: 6.0909x; 6.0909x over previous
//
#include <hip/hip_runtime.h>

#define SS 784            // 28*28

typedef float f32x4 __attribute__((ext_vector_type(4)));
typedef short s16x8 __attribute__((ext_vector_type(8)));

__device__ inline ushort f2bf(float f) {
    union { float f; unsigned u; } v; v.f = f;
    unsigned r = (v.u + 0x7fff + ((v.u >> 16) & 1)) >> 16;
    return (ushort)r;
}

// ---------------- input projections (f32 compute, bf16 layout-aware epilogue) -------------
// MODE 0: Q  -> qt[b][p][o] bf16, scaled
// MODE 1: KV -> o<256: kt[b][p][o] bf16 ; o>=256: vv[b][o-256][p] bf16
template<int MODE>
__global__ __launch_bounds__(256) void proj_in(const float* __restrict__ X,
                                               const float* __restrict__ W,
                                               const float* __restrict__ bias,
                                               ushort* __restrict__ t_out,   // qt or kt
                                               ushort* __restrict__ v_out,   // vv (MODE 1)
                                               float scale) {
    __shared__ __align__(16) float Ws[16][68];
    __shared__ __align__(16) float Xs[16][64];
    const int tid = threadIdx.x;
    const int tx = tid & 15;
    const int ty = tid >> 4;
    const int p0 = blockIdx.x * 64;
    const int o0 = blockIdx.y * 64;
    const int b  = blockIdx.z;
    const int CIN = 512;

    float acc[4][4] = {};
    const float* Xb = X + (size_t)b * CIN * SS;

    for (int c0 = 0; c0 < CIN; c0 += 16) {
        __syncthreads();
        #pragma unroll
        for (int i = 0; i < 4; ++i) {
            int idx = tid + 256 * i;
            int row = idx >> 4;
            int col = idx & 15;
            Ws[col][row] = W[(size_t)(o0 + row) * CIN + c0 + col];
        }
        #pragma unroll
        for (int i = 0; i < 4; ++i) {
            int idx = tid + 256 * i;
            int row = idx >> 6;
            int col = idx & 63;
            int p = p0 + col;
            Xs[row][col] = (p < SS) ? Xb[(size_t)(c0 + row) * SS + p] : 0.0f;
        }
        __syncthreads();
        #pragma unroll
        for (int kk = 0; kk < 16; ++kk) {
            float4 a4 = *(const float4*)&Ws[kk][ty * 4];
            float4 x4 = *(const float4*)&Xs[kk][tx * 4];
            acc[0][0] += a4.x * x4.x; acc[0][1] += a4.x * x4.y; acc[0][2] += a4.x * x4.z; acc[0][3] += a4.x * x4.w;
            acc[1][0] += a4.y * x4.x; acc[1][1] += a4.y * x4.y; acc[1][2] += a4.y * x4.z; acc[1][3] += a4.y * x4.w;
            acc[2][0] += a4.z * x4.x; acc[2][1] += a4.z * x4.y; acc[2][2] += a4.z * x4.z; acc[2][3] += a4.z * x4.w;
            acc[3][0] += a4.w * x4.x; acc[3][1] += a4.w * x4.y; acc[3][2] += a4.w * x4.z; acc[3][3] += a4.w * x4.w;
        }
    }

    float bv[4];
    #pragma unroll
    for (int i = 0; i < 4; ++i) bv[i] = bias[o0 + ty * 4 + i];

    bool kpath = (MODE == 0) || (o0 < 256);
    if (kpath) {
        // transposed bf16 write: t_out[b][p][o]
        #pragma unroll
        for (int j = 0; j < 4; ++j) {
            int p = p0 + tx * 4 + j;
            if (p < SS) {
                ushort4 w4;
                w4.x = f2bf((acc[0][j] + bv[0]) * scale);
                w4.y = f2bf((acc[1][j] + bv[1]) * scale);
                w4.z = f2bf((acc[2][j] + bv[2]) * scale);
                w4.w = f2bf((acc[3][j] + bv[3]) * scale);
                *(ushort4*)&t_out[((size_t)b * SS + p) * 256 + o0 + ty * 4] = w4;
            }
        }
    } else {
        // V: normal layout bf16: v_out[b][o-256][p]
        if (p0 + tx * 4 < SS) {
            #pragma unroll
            for (int i = 0; i < 4; ++i) {
                int o = o0 + ty * 4 + i - 256;
                ushort4 w4;
                w4.x = f2bf(acc[i][0] + bv[i]);
                w4.y = f2bf(acc[i][1] + bv[i]);
                w4.z = f2bf(acc[i][2] + bv[i]);
                w4.w = f2bf(acc[i][3] + bv[i]);
                *(ushort4*)&v_out[((size_t)b * 256 + o) * SS + p0 + tx * 4] = w4;
            }
        }
    }
}

// ---------------- output projection (f32, unchanged structure) ----------------
__global__ __launch_bounds__(256) void proj_out(const float* __restrict__ X,
                                                const float* __restrict__ W,
                                                const float* __restrict__ bias,
                                                float* __restrict__ Out) {
    __shared__ __align__(16) float Ws[16][68];
    __shared__ __align__(16) float Xs[16][64];
    const int tid = threadIdx.x;
    const int tx = tid & 15;
    const int ty = tid >> 4;
    const int p0 = blockIdx.x * 64;
    const int o0 = blockIdx.y * 64;
    const int b  = blockIdx.z;
    const int CIN = 256;

    float acc[4][4] = {};
    const float* Xb = X + (size_t)b * CIN * SS;

    for (int c0 = 0; c0 < CIN; c0 += 16) {
        __syncthreads();
        #pragma unroll
        for (int i = 0; i < 4; ++i) {
            int idx = tid + 256 * i;
            int row = idx >> 4;
            int col = idx & 15;
            Ws[col][row] = W[(size_t)(o0 + row) * CIN + c0 + col];
        }
        #pragma unroll
        for (int i = 0; i < 4; ++i) {
            int idx = tid + 256 * i;
            int row = idx >> 6;
            int col = idx & 63;
            int p = p0 + col;
            Xs[row][col] = (p < SS) ? Xb[(size_t)(c0 + row) * SS + p] : 0.0f;
        }
        __syncthreads();
        #pragma unroll
        for (int kk = 0; kk < 16; ++kk) {
            float4 a4 = *(const float4*)&Ws[kk][ty * 4];
            float4 x4 = *(const float4*)&Xs[kk][tx * 4];
            acc[0][0] += a4.x * x4.x; acc[0][1] += a4.x * x4.y; acc[0][2] += a4.x * x4.z; acc[0][3] += a4.x * x4.w;
            acc[1][0] += a4.y * x4.x; acc[1][1] += a4.y * x4.y; acc[1][2] += a4.y * x4.z; acc[1][3] += a4.y * x4.w;
            acc[2][0] += a4.z * x4.x; acc[2][1] += a4.z * x4.y; acc[2][2] += a4.z * x4.z; acc[2][3] += a4.z * x4.w;
            acc[3][0] += a4.w * x4.x; acc[3][1] += a4.w * x4.y; acc[3][2] += a4.w * x4.z; acc[3][3] += a4.w * x4.w;
        }
    }

    #pragma unroll
    for (int i = 0; i < 4; ++i) {
        int o = o0 + ty * 4 + i;
        float bv = bias[o];
        #pragma unroll
        for (int j = 0; j < 4; ++j) {
            int p = p0 + tx * 4 + j;
            if (p < SS)
                Out[((size_t)b * 512 + o) * SS + p] = acc[i][j] + bv;
        }
    }
}

// ---------------- fused MFMA attention ----------------
// Workgroup: (b, s-tile of 64), 4 waves, wave w owns s-strip s0 = tile*64 + w*16.
// Loop t-tiles of 32. Per tile/wave: 8 heads x 2 t-half logits MFMAs (K=32 = one head's d),
// head-softmax fully lane-local, P -> LDS bounce -> PV MFMAs.
#define KROW 264   // 256 + 8 pad (528B rows = odd multiple of 16B -> conflict-free b128 column reads)
#define VROW 56    // 32 + 24 pad (112B rows)
#define PROW 56

__global__ __launch_bounds__(256) void attn_mfma(const ushort* __restrict__ qt,
                                                 const ushort* __restrict__ kt,
                                                 const ushort* __restrict__ vv,
                                                 float* __restrict__ attn2) {
    __shared__ ushort ks[32 * KROW];         // 16.9 KB
    __shared__ ushort vs[256 * VROW];        // 28.7 KB
    __shared__ ushort ps[4 * 8 * 16 * PROW]; // per-wave per-head P tiles, 57.3 KB
    const int tid  = threadIdx.x;
    const int lane = tid & 63;
    const int wave = tid >> 6;
    const int b     = blockIdx.x / 13;
    const int stile = blockIdx.x % 13;
    int strip = stile * 4 + wave;
    const bool valid = (strip < 49);
    if (!valid) strip = 48;
    const int s0 = strip * 16;

    const int lg = lane >> 4;   // 0..3
    const int lm = lane & 15;

    const s16x8 Z8 = {0,0,0,0,0,0,0,0};
    const f32x4 Z4 = {0.f,0.f,0.f,0.f};

    // Q fragments (A-operand), one per head: lane reads q[s0+lm][n*32 + 8*lg .. +7]
    s16x8 qf[8];
    const ushort* qbase = qt + ((size_t)b * SS + s0 + lm) * 256 + 8 * lg;
    #pragma unroll
    for (int n = 0; n < 8; ++n)
        qf[n] = *(const s16x8*)(qbase + n * 32);

    f32x4 oacc[8][2];
    #pragma unroll
    for (int n = 0; n < 8; ++n) { oacc[n][0] = Z4; oacc[n][1] = Z4; }

    const ushort* ktb = kt + (size_t)b * SS * 256;
    const ushort* vb  = vv + (size_t)b * 256 * SS;
    ushort* pw = ps + wave * 8 * 16 * PROW;

    for (int t0 = 0; t0 < SS; t0 += 32) {
        __syncthreads();
        // stage K tile: [32 t][256 c]
        #pragma unroll
        for (int it = 0; it < 4; ++it) {
            int idx = tid + 256 * it;
            int row = idx >> 5;
            int ch8 = (idx & 31) * 8;
            int t = t0 + row;
            s16x8 val = (t < SS) ? *(const s16x8*)(ktb + (size_t)t * 256 + ch8) : Z8;
            *(s16x8*)&ks[row * KROW + ch8] = val;
        }
        // stage V tile: [256 c][32 t]
        #pragma unroll
        for (int it = 0; it < 4; ++it) {
            int idx = tid + 256 * it;
            int c  = idx >> 2;
            int t8 = (idx & 3) * 8;
            int t = t0 + t8;
            s16x8 val = (t < SS) ? *(const s16x8*)(vb + (size_t)c * SS + t) : Z8;
            *(s16x8*)&vs[c * VROW + t8] = val;
        }
        __syncthreads();

        // logits: 8 heads x 2 t-halves, one MFMA each (K=32 = full head depth)
        f32x4 lacc[8][2];
        #pragma unroll
        for (int n = 0; n < 8; ++n) {
            #pragma unroll
            for (int h = 0; h < 2; ++h) {
                s16x8 bk = *(const s16x8*)&ks[(h * 16 + lm) * KROW + n * 32 + 8 * lg];
                lacc[n][h] = __builtin_amdgcn_mfma_f32_16x16x32_bf16(qf[n], bk, Z4, 0, 0, 0);
            }
        }

        // softmax over heads (lane-local!) + write P to LDS (bf16, A-layout-friendly)
        #pragma unroll
        for (int h = 0; h < 2; ++h) {
            #pragma unroll
            for (int r = 0; r < 4; ++r) {
                float m = lacc[0][h][r];
                #pragma unroll
                for (int n = 1; n < 8; ++n) m = fmaxf(m, lacc[n][h][r]);
                float e[8]; float sum = 0.f;
                #pragma unroll
                for (int n = 0; n < 8; ++n) { e[n] = __expf(lacc[n][h][r] - m); sum += e[n]; }
                float inv = 1.0f / sum;
                int srow = 4 * lg + r;
                int tcol = lm + 16 * h;
                #pragma unroll
                for (int n = 0; n < 8; ++n)
                    pw[(n * 16 + srow) * PROW + tcol] = f2bf(e[n] * inv);
            }
        }

        // PV: out[s][d] += P[s][t] * V[t][d]; per head 2 d-half MFMAs
        #pragma unroll
        for (int n = 0; n < 8; ++n) {
            s16x8 aw = *(const s16x8*)&ps[wave * 8 * 16 * PROW + (n * 16 + lm) * PROW + 8 * lg];
            #pragma unroll
            for (int dh = 0; dh < 2; ++dh) {
                s16x8 bv8 = *(const s16x8*)&vs[(n * 32 + dh * 16 + lm) * VROW + 8 * lg];
                oacc[n][dh] = __builtin_amdgcn_mfma_f32_16x16x32_bf16(aw, bv8, oacc[n][dh], 0, 0, 0);
            }
        }
    }

    // write attn2 f32 with the reference reshape quirk folded in
    if (valid) {
        #pragma unroll
        for (int n = 0; n < 8; ++n) {
            #pragma unroll
            for (int dh = 0; dh < 2; ++dh) {
                #pragma unroll
                for (int r = 0; r < 4; ++r) {
                    int d = dh * 16 + lm;
                    int s = s0 + 4 * lg + r;
                    int f = s * 32 + d;
                    int e = f / SS;
                    int p = f - e * SS;
                    attn2[((size_t)b * 256 + n * 32 + e) * SS + p] = oacc[n][dh][r];
                }
            }
        }
    }
}

extern "C" void kernel_launch(void* const* d_in, const int* in_sizes, int n_in,
                              void* d_out, int out_size, void* d_ws, size_t ws_size,
                              hipStream_t stream) {
    const float* inputs    = (const float*)d_in[0];
    const float* inputs_st = (const float*)d_in[1];
    const float* Wq        = (const float*)d_in[2];
    const float* bq        = (const float*)d_in[3];
    const float* Wkv       = (const float*)d_in[4];
    const float* bkv       = (const float*)d_in[5];
    const float* Wo        = (const float*)d_in[6];
    const float* bo        = (const float*)d_in[7];
    float* out = (float*)d_out;

    const size_t NBS = (size_t)8 * SS * 256;       // 1,605,632 elems
    ushort* qt  = (ushort*)d_ws;
    ushort* ktw = qt + NBS;
    ushort* vw  = ktw + NBS;
    float* attn2 = (float*)(vw + NBS);             // 6.4 MB f32

    proj_in<0><<<dim3(13, 4, 8), dim3(256), 0, stream>>>(inputs, Wq, bq, qt, nullptr, 0.17677669529663687f);
    proj_in<1><<<dim3(13, 8, 8), dim3(256), 0, stream>>>(inputs_st, Wkv, bkv, ktw, vw, 1.0f);
    attn_mfma<<<dim3(104), dim3(256), 0, stream>>>(qt, ktw, vw, attn2);
    proj_out<<<dim3(13, 8, 8), dim3(256), 0, stream>>>(attn2, Wo, bo, out);
}

// Round 3
// 193.858 us; speedup vs baseline: 9.7639x; 1.6030x over previous
//
#include <hip/hip_runtime.h>

#define SS 784
#define NQE 1605632          // 8*784*256 (elements of one bf16 [b][p][256] buffer)

typedef float f32x4 __attribute__((ext_vector_type(4)));
typedef short s16x8 __attribute__((ext_vector_type(8)));

__device__ inline ushort f2bf(float f) {
    union { float f; unsigned u; } v; v.f = f;
    return (ushort)((v.u + 0x7fff + ((v.u >> 16) & 1)) >> 16);
}
__device__ inline float bf2f(ushort h) {
    union { unsigned u; float f; } v; v.u = ((unsigned)h) << 16;
    return v.f;
}

// ---------------- transpose + f32->bf16: X[b][c][p] -> Xt[b][p][c] ----------------
__global__ __launch_bounds__(256) void transpose_cvt(const float* __restrict__ X,
                                                     ushort* __restrict__ Xt) {
    __shared__ ushort Ts[64][72];   // 144B rows = 9*16B (odd multiple of 16) -> low conflict
    const int tid = threadIdx.x;
    const int p0 = blockIdx.x * 64, c0 = blockIdx.y * 64, b = blockIdx.z;
    const int cr = tid >> 2, ch = (tid & 3) * 16;
    if (p0 + ch < SS) {                       // SS is a multiple of 16 -> whole-chunk guard
        const float* src = X + ((size_t)b * 512 + c0 + cr) * SS + p0 + ch;
        #pragma unroll
        for (int jj = 0; jj < 4; ++jj) {
            float4 v = *(const float4*)(src + jj * 4);
            Ts[ch + jj * 4 + 0][cr] = f2bf(v.x);
            Ts[ch + jj * 4 + 1][cr] = f2bf(v.y);
            Ts[ch + jj * 4 + 2][cr] = f2bf(v.z);
            Ts[ch + jj * 4 + 3][cr] = f2bf(v.w);
        }
    } else {
        #pragma unroll
        for (int j = 0; j < 16; ++j) Ts[ch + j][cr] = 0;
    }
    __syncthreads();
    const int pr = tid >> 2, cc = (tid & 3) * 16;
    if (p0 + pr < SS) {
        ushort* dst = Xt + ((size_t)b * SS + p0 + pr) * 512 + c0 + cc;
        *(s16x8*)dst       = *(const s16x8*)&Ts[pr][cc];
        *(s16x8*)(dst + 8) = *(const s16x8*)&Ts[pr][cc + 8];
    }
}

// ---------------- Q/K projection: D[o][p] = W[o][:]·Xt[p][:] ; out bf16 [b][p][o] ----------------
__global__ __launch_bounds__(256) void gemm_qk(const ushort* __restrict__ Xt,
                                               const float* __restrict__ Wg,   // [M>=o0+128][512]
                                               const float* __restrict__ bias,
                                               ushort* __restrict__ outT,      // [b][p][256]
                                               float scale) {
    __shared__ ushort As[128 * 40];   // 80B rows (5*16, odd) -> conflict-free b128 col reads
    __shared__ ushort Bs[128 * 40];
    const int tid = threadIdx.x;
    const int lane = tid & 63, wave = tid >> 6;
    const int wm = wave >> 1, wn = wave & 1;
    const int lg = lane >> 4, lm = lane & 15;
    const int p0 = blockIdx.x * 128;
    const int o0 = blockIdx.y * 128;
    const int b  = blockIdx.z;
    const int srow = tid >> 1, shalf = (tid & 1) * 16;

    const f32x4 Z4 = {0.f, 0.f, 0.f, 0.f};
    const s16x8 Z8 = {0, 0, 0, 0, 0, 0, 0, 0};
    f32x4 acc[4][4];
    #pragma unroll
    for (int m = 0; m < 4; ++m)
        #pragma unroll
        for (int n = 0; n < 4; ++n) acc[m][n] = Z4;

    for (int c0 = 0; c0 < 512; c0 += 32) {
        __syncthreads();
        {   // A: W f32 -> bf16
            const float* src = Wg + (size_t)(o0 + srow) * 512 + c0 + shalf;
            ushort tmp[16];
            #pragma unroll
            for (int jj = 0; jj < 4; ++jj) {
                float4 v = *(const float4*)(src + jj * 4);
                tmp[jj * 4 + 0] = f2bf(v.x); tmp[jj * 4 + 1] = f2bf(v.y);
                tmp[jj * 4 + 2] = f2bf(v.z); tmp[jj * 4 + 3] = f2bf(v.w);
            }
            *(s16x8*)&As[srow * 40 + shalf]     = *(s16x8*)&tmp[0];
            *(s16x8*)&As[srow * 40 + shalf + 8] = *(s16x8*)&tmp[8];
        }
        {   // B: Xt bf16 copy
            int p = p0 + srow;
            s16x8 v0 = Z8, v1 = Z8;
            if (p < SS) {
                const ushort* src = Xt + ((size_t)b * SS + p) * 512 + c0 + shalf;
                v0 = *(const s16x8*)src;
                v1 = *(const s16x8*)(src + 8);
            }
            *(s16x8*)&Bs[srow * 40 + shalf]     = v0;
            *(s16x8*)&Bs[srow * 40 + shalf + 8] = v1;
        }
        __syncthreads();
        s16x8 af[4], bf[4];
        #pragma unroll
        for (int m = 0; m < 4; ++m) af[m] = *(const s16x8*)&As[(wm * 64 + m * 16 + lm) * 40 + 8 * lg];
        #pragma unroll
        for (int n = 0; n < 4; ++n) bf[n] = *(const s16x8*)&Bs[(wn * 64 + n * 16 + lm) * 40 + 8 * lg];
        #pragma unroll
        for (int m = 0; m < 4; ++m)
            #pragma unroll
            for (int n = 0; n < 4; ++n)
                acc[m][n] = __builtin_amdgcn_mfma_f32_16x16x32_bf16(af[m], bf[n], acc[m][n], 0, 0, 0);
    }

    #pragma unroll
    for (int m = 0; m < 4; ++m) {
        const int o = o0 + wm * 64 + m * 16 + 4 * lg;
        float bv[4];
        #pragma unroll
        for (int r = 0; r < 4; ++r) bv[r] = bias[o + r];
        #pragma unroll
        for (int n = 0; n < 4; ++n) {
            const int p = p0 + wn * 64 + n * 16 + lm;
            if (p < SS) {
                ushort4 w;
                w.x = f2bf((acc[m][n][0] + bv[0]) * scale);
                w.y = f2bf((acc[m][n][1] + bv[1]) * scale);
                w.z = f2bf((acc[m][n][2] + bv[2]) * scale);
                w.w = f2bf((acc[m][n][3] + bv[3]) * scale);
                *(ushort4*)&outT[((size_t)b * SS + p) * 256 + o] = w;
            }
        }
    }
}

// ---------------- generic: D[p][o] = A[p][:]·W[o][:] ; A bf16 [b][p][KD], W f32 [NCH][KD] ----------------
// OUTF32=false: out bf16 [b][NCH][SS]  (V) ; OUTF32=true: out f32 [b][NCH][SS] (final)
template<int KD, int NCH, bool OUTF32>
__global__ __launch_bounds__(256) void gemm_pn(const ushort* __restrict__ A,
                                               const float* __restrict__ Wg,
                                               const float* __restrict__ bias,
                                               void* __restrict__ outp) {
    __shared__ ushort As[128 * 40];
    __shared__ ushort Bs[128 * 40];
    const int tid = threadIdx.x;
    const int lane = tid & 63, wave = tid >> 6;
    const int wm = wave >> 1, wn = wave & 1;
    const int lg = lane >> 4, lm = lane & 15;
    const int o0 = blockIdx.x * 128;   // N (output channels)
    const int p0 = blockIdx.y * 128;   // M (positions)
    const int b  = blockIdx.z;
    const int srow = tid >> 1, shalf = (tid & 1) * 16;

    const f32x4 Z4 = {0.f, 0.f, 0.f, 0.f};
    const s16x8 Z8 = {0, 0, 0, 0, 0, 0, 0, 0};
    f32x4 acc[4][4];
    #pragma unroll
    for (int m = 0; m < 4; ++m)
        #pragma unroll
        for (int n = 0; n < 4; ++n) acc[m][n] = Z4;

    for (int c0 = 0; c0 < KD; c0 += 32) {
        __syncthreads();
        {   // A: bf16 [p][KD]
            int p = p0 + srow;
            s16x8 v0 = Z8, v1 = Z8;
            if (p < SS) {
                const ushort* src = A + ((size_t)b * SS + p) * KD + c0 + shalf;
                v0 = *(const s16x8*)src;
                v1 = *(const s16x8*)(src + 8);
            }
            *(s16x8*)&As[srow * 40 + shalf]     = v0;
            *(s16x8*)&As[srow * 40 + shalf + 8] = v1;
        }
        {   // B: W f32 -> bf16
            const float* src = Wg + (size_t)(o0 + srow) * KD + c0 + shalf;
            ushort tmp[16];
            #pragma unroll
            for (int jj = 0; jj < 4; ++jj) {
                float4 v = *(const float4*)(src + jj * 4);
                tmp[jj * 4 + 0] = f2bf(v.x); tmp[jj * 4 + 1] = f2bf(v.y);
                tmp[jj * 4 + 2] = f2bf(v.z); tmp[jj * 4 + 3] = f2bf(v.w);
            }
            *(s16x8*)&Bs[srow * 40 + shalf]     = *(s16x8*)&tmp[0];
            *(s16x8*)&Bs[srow * 40 + shalf + 8] = *(s16x8*)&tmp[8];
        }
        __syncthreads();
        s16x8 af[4], bf[4];
        #pragma unroll
        for (int m = 0; m < 4; ++m) af[m] = *(const s16x8*)&As[(wm * 64 + m * 16 + lm) * 40 + 8 * lg];
        #pragma unroll
        for (int n = 0; n < 4; ++n) bf[n] = *(const s16x8*)&Bs[(wn * 64 + n * 16 + lm) * 40 + 8 * lg];
        #pragma unroll
        for (int m = 0; m < 4; ++m)
            #pragma unroll
            for (int n = 0; n < 4; ++n)
                acc[m][n] = __builtin_amdgcn_mfma_f32_16x16x32_bf16(af[m], bf[n], acc[m][n], 0, 0, 0);
    }

    // D rows = p, cols = o ; writes vectorized along p
    #pragma unroll
    for (int n = 0; n < 4; ++n) {
        const int o = o0 + wn * 64 + n * 16 + lm;
        const float bv = bias[o];
        #pragma unroll
        for (int m = 0; m < 4; ++m) {
            const int p = p0 + wm * 64 + m * 16 + 4 * lg;
            if (p < SS) {     // p multiple of 4, SS multiple of 16 -> covers p..p+3
                if (OUTF32) {
                    f32x4 v;
                    #pragma unroll
                    for (int r = 0; r < 4; ++r) v[r] = acc[m][n][r] + bv;
                    *(f32x4*)&((float*)outp)[((size_t)b * NCH + o) * SS + p] = v;
                } else {
                    ushort4 w;
                    w.x = f2bf(acc[m][n][0] + bv);
                    w.y = f2bf(acc[m][n][1] + bv);
                    w.z = f2bf(acc[m][n][2] + bv);
                    w.w = f2bf(acc[m][n][3] + bv);
                    *(ushort4*)&((ushort*)outp)[((size_t)b * NCH + o) * SS + p] = w;
                }
            }
        }
    }
}

// ---------------- fused MFMA attention, t-split over 5 partial buffers ----------------
#define KROW 264   // 528B rows (33*16, odd)
#define VROW 40    // 80B rows
#define PROW 40

__global__ __launch_bounds__(256) void attn_mfma(const ushort* __restrict__ qt,
                                                 const ushort* __restrict__ kt,
                                                 const ushort* __restrict__ vv,
                                                 ushort* __restrict__ pb,   // partials 0..3, stride NQE
                                                 ushort* __restrict__ p4) {
    __shared__ ushort ks[32 * KROW];          // 16896 B
    __shared__ ushort vs[256 * VROW];         // 20480 B
    __shared__ ushort ps[4 * 8 * 16 * PROW];  // 40960 B
    const int tid  = threadIdx.x;
    const int lane = tid & 63;
    const int wave = tid >> 6;
    const int b     = blockIdx.y;
    const int stile = blockIdx.x / 5;
    const int ts    = blockIdx.x % 5;
    int strip = stile * 4 + wave;
    const bool valid = (strip < 49);
    if (!valid) strip = 48;
    const int s0 = strip * 16;

    const int lg = lane >> 4, lm = lane & 15;
    const s16x8 Z8 = {0, 0, 0, 0, 0, 0, 0, 0};
    const f32x4 Z4 = {0.f, 0.f, 0.f, 0.f};

    s16x8 qf[8];
    const ushort* qbase = qt + ((size_t)b * SS + s0 + lm) * 256 + 8 * lg;
    #pragma unroll
    for (int n = 0; n < 8; ++n) qf[n] = *(const s16x8*)(qbase + n * 32);

    f32x4 oacc[8][2];
    #pragma unroll
    for (int n = 0; n < 8; ++n) { oacc[n][0] = Z4; oacc[n][1] = Z4; }

    const ushort* ktb = kt + (size_t)b * SS * 256;
    const ushort* vb  = vv + (size_t)b * 256 * SS;
    ushort* pw = ps + wave * (8 * 16 * PROW);

    for (int ti = ts * 5; ti < ts * 5 + 5; ++ti) {
        const int t0 = ti * 32;
        __syncthreads();
        {   // K tile [32 t][256 c]
            const int row = tid >> 3, ce = (tid & 7) * 32;
            const int t = t0 + row;
            const ushort* src = ktb + (size_t)t * 256 + ce;
            #pragma unroll
            for (int j = 0; j < 4; ++j) {
                s16x8 v = (t < SS) ? *(const s16x8*)(src + 8 * j) : Z8;
                *(s16x8*)&ks[row * KROW + ce + 8 * j] = v;
            }
        }
        {   // V tile [256 c][32 t]
            const ushort* src = vb + (size_t)tid * SS + t0;
            #pragma unroll
            for (int j = 0; j < 4; ++j) {
                s16x8 v = (t0 + 8 * j < SS) ? *(const s16x8*)(src + 8 * j) : Z8;
                *(s16x8*)&vs[tid * VROW + 8 * j] = v;
            }
        }
        __syncthreads();

        // logits (already in log2 domain via qscale)
        f32x4 lacc[8][2];
        #pragma unroll
        for (int n = 0; n < 8; ++n) {
            #pragma unroll
            for (int h = 0; h < 2; ++h) {
                s16x8 bk = *(const s16x8*)&ks[(h * 16 + lm) * KROW + n * 32 + 8 * lg];
                lacc[n][h] = __builtin_amdgcn_mfma_f32_16x16x32_bf16(qf[n], bk, Z4, 0, 0, 0);
            }
        }

        // head-axis softmax, lane-local; P -> LDS (bf16)
        #pragma unroll
        for (int h = 0; h < 2; ++h) {
            #pragma unroll
            for (int r = 0; r < 4; ++r) {
                float m = lacc[0][h][r];
                #pragma unroll
                for (int n = 1; n < 8; ++n) m = fmaxf(m, lacc[n][h][r]);
                float e[8]; float sum = 0.f;
                #pragma unroll
                for (int n = 0; n < 8; ++n) { e[n] = exp2f(lacc[n][h][r] - m); sum += e[n]; }
                float inv;
                asm("v_rcp_f32 %0, %1" : "=v"(inv) : "v"(sum));
                const int srow = 4 * lg + r, tcol = h * 16 + lm;
                #pragma unroll
                for (int n = 0; n < 8; ++n)
                    pw[(n * 16 + srow) * PROW + tcol] = f2bf(e[n] * inv);
            }
        }

        // PV
        #pragma unroll
        for (int n = 0; n < 8; ++n) {
            s16x8 aw = *(const s16x8*)&pw[(n * 16 + lm) * PROW + 8 * lg];
            #pragma unroll
            for (int dh = 0; dh < 2; ++dh) {
                s16x8 bv8 = *(const s16x8*)&vs[(n * 32 + dh * 16 + lm) * VROW + 8 * lg];
                oacc[n][dh] = __builtin_amdgcn_mfma_f32_16x16x32_bf16(aw, bv8, oacc[n][dh], 0, 0, 0);
            }
        }
    }

    if (valid) {
        ushort* part = (ts < 4) ? (pb + (size_t)ts * NQE) : p4;
        #pragma unroll
        for (int n = 0; n < 8; ++n)
            #pragma unroll
            for (int dh = 0; dh < 2; ++dh)
                #pragma unroll
                for (int r = 0; r < 4; ++r) {
                    const int d = dh * 16 + lm;
                    const int s = s0 + 4 * lg + r;
                    const int f = s * 32 + d;
                    const int e = f / SS;
                    const int p = f - e * SS;
                    part[((size_t)b * SS + p) * 256 + n * 32 + e] = f2bf(oacc[n][dh][r]);
                }
    }
}

// ---------------- sum the 5 bf16 partials -> bf16 ----------------
__global__ __launch_bounds__(256) void sum5(const ushort* __restrict__ a0,
                                            const ushort* __restrict__ a1,
                                            const ushort* __restrict__ a2,
                                            const ushort* __restrict__ a3,
                                            const ushort* __restrict__ a4,
                                            ushort* __restrict__ outb) {
    const size_t i = ((size_t)blockIdx.x * 256 + threadIdx.x) * 8;
    s16x8 v0 = *(const s16x8*)(a0 + i);
    s16x8 v1 = *(const s16x8*)(a1 + i);
    s16x8 v2 = *(const s16x8*)(a2 + i);
    s16x8 v3 = *(const s16x8*)(a3 + i);
    s16x8 v4 = *(const s16x8*)(a4 + i);
    s16x8 t;
    #pragma unroll
    for (int j = 0; j < 8; ++j) {
        float s = bf2f((ushort)v0[j]) + bf2f((ushort)v1[j]) + bf2f((ushort)v2[j])
                + bf2f((ushort)v3[j]) + bf2f((ushort)v4[j]);
        t[j] = (short)f2bf(s);
    }
    *(s16x8*)(outb + i) = t;
}

extern "C" void kernel_launch(void* const* d_in, const int* in_sizes, int n_in,
                              void* d_out, int out_size, void* d_ws, size_t ws_size,
                              hipStream_t stream) {
    const float* inputs    = (const float*)d_in[0];
    const float* inputs_st = (const float*)d_in[1];
    const float* Wq        = (const float*)d_in[2];
    const float* bq        = (const float*)d_in[3];
    const float* Wkv       = (const float*)d_in[4];
    const float* bkv       = (const float*)d_in[5];
    const float* Wo        = (const float*)d_in[6];
    const float* bo        = (const float*)d_in[7];
    float* out = (float*)d_out;

    // ws map (ushort units). NQE = 8*784*256. Total 8*NQE*2 B = 25,690,112 B.
    ushort* W     = (ushort*)d_ws;
    ushort* xt_q  = W;               // [0, 2NQE)   (later reused as partials 0,1)
    ushort* xt_kv = W + 2 * (size_t)NQE;  // [2NQE,4NQE) (later partials 2,3)
    ushort* qt    = W + 4 * (size_t)NQE;  // (later reused as summed attn)
    ushort* kt    = W + 5 * (size_t)NQE;
    ushort* vv    = W + 6 * (size_t)NQE;
    ushort* p4    = W + 7 * (size_t)NQE;
    ushort* sumb  = qt;

    const float qscale = (float)(1.4426950408889634 / 5.656854249492380195); // log2(e)/sqrt(32)

    transpose_cvt<<<dim3(13, 8, 8), dim3(256), 0, stream>>>(inputs, xt_q);
    transpose_cvt<<<dim3(13, 8, 8), dim3(256), 0, stream>>>(inputs_st, xt_kv);
    gemm_qk<<<dim3(7, 2, 8), dim3(256), 0, stream>>>(xt_q, Wq, bq, qt, qscale);
    gemm_qk<<<dim3(7, 2, 8), dim3(256), 0, stream>>>(xt_kv, Wkv, bkv, kt, 1.0f);
    gemm_pn<512, 256, false><<<dim3(2, 7, 8), dim3(256), 0, stream>>>(xt_kv, Wkv + 256 * 512, bkv + 256, vv);
    attn_mfma<<<dim3(65, 8), dim3(256), 0, stream>>>(qt, kt, vv, W, p4);
    sum5<<<dim3(784), dim3(256), 0, stream>>>(W, W + (size_t)NQE, W + 2 * (size_t)NQE,
                                              W + 3 * (size_t)NQE, p4, sumb);
    gemm_pn<256, 512, true><<<dim3(4, 7, 8), dim3(256), 0, stream>>>(sumb, Wo, bo, out);
}

// Round 4
// 151.811 us; speedup vs baseline: 12.4682x; 1.2770x over previous
//
#include <hip/hip_runtime.h>

#define SS 784
#define NQE 1605632          // 8*784*256 (elements of one bf16 buffer)

typedef float f32x4 __attribute__((ext_vector_type(4)));
typedef short s16x8 __attribute__((ext_vector_type(8)));

__device__ inline ushort f2bf(float f) {
    union { float f; unsigned u; } v; v.f = f;
    return (ushort)((v.u + 0x7fff + ((v.u >> 16) & 1)) >> 16);
}
__device__ inline float bf2f(ushort h) {
    union { unsigned u; float f; } v; v.u = ((unsigned)h) << 16;
    return v.f;
}

// ---------------- transpose + f32->bf16: X[b][c][p] -> Xt[b][p][c] ----------------
__global__ __launch_bounds__(256) void transpose_cvt(const float* __restrict__ X,
                                                     ushort* __restrict__ Xt) {
    __shared__ ushort Ts[64][72];   // 144B rows (9*16B, odd) -> low conflict
    const int tid = threadIdx.x;
    const int p0 = blockIdx.x * 64, c0 = blockIdx.y * 64, b = blockIdx.z;
    const int cr = tid >> 2, ch = (tid & 3) * 16;
    if (p0 + ch < SS) {                       // SS multiple of 16 -> whole-chunk guard
        const float* src = X + ((size_t)b * 512 + c0 + cr) * SS + p0 + ch;
        #pragma unroll
        for (int jj = 0; jj < 4; ++jj) {
            float4 v = *(const float4*)(src + jj * 4);
            Ts[ch + jj * 4 + 0][cr] = f2bf(v.x);
            Ts[ch + jj * 4 + 1][cr] = f2bf(v.y);
            Ts[ch + jj * 4 + 2][cr] = f2bf(v.z);
            Ts[ch + jj * 4 + 3][cr] = f2bf(v.w);
        }
    } else {
        #pragma unroll
        for (int j = 0; j < 16; ++j) Ts[ch + j][cr] = 0;
    }
    __syncthreads();
    const int pr = tid >> 2, cc = (tid & 3) * 16;
    if (p0 + pr < SS) {
        ushort* dst = Xt + ((size_t)b * SS + p0 + pr) * 512 + c0 + cc;
        *(s16x8*)dst       = *(const s16x8*)&Ts[pr][cc];
        *(s16x8*)(dst + 8) = *(const s16x8*)&Ts[pr][cc + 8];
    }
}

// ---------------- Q/K projection: D[o][p] = W[o][:]·Xt[p][:] ; out bf16 [b][p][o] ----------------
__global__ __launch_bounds__(256) void gemm_qk(const ushort* __restrict__ Xt,
                                               const float* __restrict__ Wg,
                                               const float* __restrict__ bias,
                                               ushort* __restrict__ outT,      // [b][p][256]
                                               float scale) {
    __shared__ ushort As[128 * 40];   // 80B rows (5*16, odd) -> conflict-free b128 col reads
    __shared__ ushort Bs[128 * 40];
    const int tid = threadIdx.x;
    const int lane = tid & 63, wave = tid >> 6;
    const int wm = wave >> 1, wn = wave & 1;
    const int lg = lane >> 4, lm = lane & 15;
    const int p0 = blockIdx.x * 128;
    const int o0 = blockIdx.y * 128;
    const int b  = blockIdx.z;
    const int srow = tid >> 1, shalf = (tid & 1) * 16;

    const f32x4 Z4 = {0.f, 0.f, 0.f, 0.f};
    const s16x8 Z8 = {0, 0, 0, 0, 0, 0, 0, 0};
    f32x4 acc[4][4];
    #pragma unroll
    for (int m = 0; m < 4; ++m)
        #pragma unroll
        for (int n = 0; n < 4; ++n) acc[m][n] = Z4;

    for (int c0 = 0; c0 < 512; c0 += 32) {
        __syncthreads();
        {   // A: W f32 -> bf16
            const float* src = Wg + (size_t)(o0 + srow) * 512 + c0 + shalf;
            ushort tmp[16];
            #pragma unroll
            for (int jj = 0; jj < 4; ++jj) {
                float4 v = *(const float4*)(src + jj * 4);
                tmp[jj * 4 + 0] = f2bf(v.x); tmp[jj * 4 + 1] = f2bf(v.y);
                tmp[jj * 4 + 2] = f2bf(v.z); tmp[jj * 4 + 3] = f2bf(v.w);
            }
            *(s16x8*)&As[srow * 40 + shalf]     = *(s16x8*)&tmp[0];
            *(s16x8*)&As[srow * 40 + shalf + 8] = *(s16x8*)&tmp[8];
        }
        {   // B: Xt bf16 copy
            int p = p0 + srow;
            s16x8 v0 = Z8, v1 = Z8;
            if (p < SS) {
                const ushort* src = Xt + ((size_t)b * SS + p) * 512 + c0 + shalf;
                v0 = *(const s16x8*)src;
                v1 = *(const s16x8*)(src + 8);
            }
            *(s16x8*)&Bs[srow * 40 + shalf]     = v0;
            *(s16x8*)&Bs[srow * 40 + shalf + 8] = v1;
        }
        __syncthreads();
        s16x8 af[4], bf[4];
        #pragma unroll
        for (int m = 0; m < 4; ++m) af[m] = *(const s16x8*)&As[(wm * 64 + m * 16 + lm) * 40 + 8 * lg];
        #pragma unroll
        for (int n = 0; n < 4; ++n) bf[n] = *(const s16x8*)&Bs[(wn * 64 + n * 16 + lm) * 40 + 8 * lg];
        #pragma unroll
        for (int m = 0; m < 4; ++m)
            #pragma unroll
            for (int n = 0; n < 4; ++n)
                acc[m][n] = __builtin_amdgcn_mfma_f32_16x16x32_bf16(af[m], bf[n], acc[m][n], 0, 0, 0);
    }

    #pragma unroll
    for (int m = 0; m < 4; ++m) {
        const int o = o0 + wm * 64 + m * 16 + 4 * lg;
        float bv[4];
        #pragma unroll
        for (int r = 0; r < 4; ++r) bv[r] = bias[o + r];
        #pragma unroll
        for (int n = 0; n < 4; ++n) {
            const int p = p0 + wn * 64 + n * 16 + lm;
            if (p < SS) {
                ushort4 w;
                w.x = f2bf((acc[m][n][0] + bv[0]) * scale);
                w.y = f2bf((acc[m][n][1] + bv[1]) * scale);
                w.z = f2bf((acc[m][n][2] + bv[2]) * scale);
                w.w = f2bf((acc[m][n][3] + bv[3]) * scale);
                *(ushort4*)&outT[((size_t)b * SS + p) * 256 + o] = w;
            }
        }
    }
}

// ---------------- generic: D[p][o] = A[p][:]·W[o][:] ; A bf16 [b][p][KD], W f32 [NCH][KD] ----------------
template<int KD, int NCH, bool OUTF32>
__global__ __launch_bounds__(256) void gemm_pn(const ushort* __restrict__ A,
                                               const float* __restrict__ Wg,
                                               const float* __restrict__ bias,
                                               void* __restrict__ outp) {
    __shared__ ushort As[128 * 40];
    __shared__ ushort Bs[128 * 40];
    const int tid = threadIdx.x;
    const int lane = tid & 63, wave = tid >> 6;
    const int wm = wave >> 1, wn = wave & 1;
    const int lg = lane >> 4, lm = lane & 15;
    const int o0 = blockIdx.x * 128;
    const int p0 = blockIdx.y * 128;
    const int b  = blockIdx.z;
    const int srow = tid >> 1, shalf = (tid & 1) * 16;

    const f32x4 Z4 = {0.f, 0.f, 0.f, 0.f};
    const s16x8 Z8 = {0, 0, 0, 0, 0, 0, 0, 0};
    f32x4 acc[4][4];
    #pragma unroll
    for (int m = 0; m < 4; ++m)
        #pragma unroll
        for (int n = 0; n < 4; ++n) acc[m][n] = Z4;

    for (int c0 = 0; c0 < KD; c0 += 32) {
        __syncthreads();
        {   // A: bf16 [p][KD]
            int p = p0 + srow;
            s16x8 v0 = Z8, v1 = Z8;
            if (p < SS) {
                const ushort* src = A + ((size_t)b * SS + p) * KD + c0 + shalf;
                v0 = *(const s16x8*)src;
                v1 = *(const s16x8*)(src + 8);
            }
            *(s16x8*)&As[srow * 40 + shalf]     = v0;
            *(s16x8*)&As[srow * 40 + shalf + 8] = v1;
        }
        {   // B: W f32 -> bf16
            const float* src = Wg + (size_t)(o0 + srow) * KD + c0 + shalf;
            ushort tmp[16];
            #pragma unroll
            for (int jj = 0; jj < 4; ++jj) {
                float4 v = *(const float4*)(src + jj * 4);
                tmp[jj * 4 + 0] = f2bf(v.x); tmp[jj * 4 + 1] = f2bf(v.y);
                tmp[jj * 4 + 2] = f2bf(v.z); tmp[jj * 4 + 3] = f2bf(v.w);
            }
            *(s16x8*)&Bs[srow * 40 + shalf]     = *(s16x8*)&tmp[0];
            *(s16x8*)&Bs[srow * 40 + shalf + 8] = *(s16x8*)&tmp[8];
        }
        __syncthreads();
        s16x8 af[4], bf[4];
        #pragma unroll
        for (int m = 0; m < 4; ++m) af[m] = *(const s16x8*)&As[(wm * 64 + m * 16 + lm) * 40 + 8 * lg];
        #pragma unroll
        for (int n = 0; n < 4; ++n) bf[n] = *(const s16x8*)&Bs[(wn * 64 + n * 16 + lm) * 40 + 8 * lg];
        #pragma unroll
        for (int m = 0; m < 4; ++m)
            #pragma unroll
            for (int n = 0; n < 4; ++n)
                acc[m][n] = __builtin_amdgcn_mfma_f32_16x16x32_bf16(af[m], bf[n], acc[m][n], 0, 0, 0);
    }

    #pragma unroll
    for (int n = 0; n < 4; ++n) {
        const int o = o0 + wn * 64 + n * 16 + lm;
        const float bv = bias[o];
        #pragma unroll
        for (int m = 0; m < 4; ++m) {
            const int p = p0 + wm * 64 + m * 16 + 4 * lg;
            if (p < SS) {
                if (OUTF32) {
                    f32x4 v;
                    #pragma unroll
                    for (int r = 0; r < 4; ++r) v[r] = acc[m][n][r] + bv;
                    *(f32x4*)&((float*)outp)[((size_t)b * NCH + o) * SS + p] = v;
                } else {
                    ushort4 w;
                    w.x = f2bf(acc[m][n][0] + bv);
                    w.y = f2bf(acc[m][n][1] + bv);
                    w.z = f2bf(acc[m][n][2] + bv);
                    w.w = f2bf(acc[m][n][3] + bv);
                    *(ushort4*)&((ushort*)outp)[((size_t)b * NCH + o) * SS + p] = w;
                }
            }
        }
    }
}

// ---------------- fused MFMA attention, t-split; COALESCED partial writes ----------------
// Key fact: within head n, flat f = s*32+d equals e*784+p of the output reshape, so
// layout [b][c2][p] (c2=n*32+e) is linear in f: addr = b*200704 + n*25088 + f.
// A wave's (16s x 32d) tile per head is f in [s0*32, s0*32+512) -> 1KB contiguous.
#define KROW 264   // 528B rows (33*16, odd)
#define VROW 40    // 80B rows
#define PROW 40

__global__ __launch_bounds__(256) void attn_mfma(const ushort* __restrict__ qt,
                                                 const ushort* __restrict__ kt,
                                                 const ushort* __restrict__ vv,
                                                 ushort* __restrict__ pb,   // partials 0..3, stride NQE
                                                 ushort* __restrict__ p4) {
    __shared__ ushort ks[32 * KROW];
    __shared__ ushort vs[256 * VROW];
    __shared__ ushort ps[4 * 8 * 16 * PROW];
    const int tid  = threadIdx.x;
    const int lane = tid & 63;
    const int wave = tid >> 6;
    const int b     = blockIdx.y;
    const int stile = blockIdx.x / 5;
    const int ts    = blockIdx.x % 5;
    int strip = stile * 4 + wave;
    const bool valid = (strip < 49);
    if (!valid) strip = 48;
    const int s0 = strip * 16;

    const int lg = lane >> 4, lm = lane & 15;
    const s16x8 Z8 = {0, 0, 0, 0, 0, 0, 0, 0};
    const f32x4 Z4 = {0.f, 0.f, 0.f, 0.f};

    s16x8 qf[8];
    const ushort* qbase = qt + ((size_t)b * SS + s0 + lm) * 256 + 8 * lg;
    #pragma unroll
    for (int n = 0; n < 8; ++n) qf[n] = *(const s16x8*)(qbase + n * 32);

    f32x4 oacc[8][2];
    #pragma unroll
    for (int n = 0; n < 8; ++n) { oacc[n][0] = Z4; oacc[n][1] = Z4; }

    const ushort* ktb = kt + (size_t)b * SS * 256;
    const ushort* vb  = vv + (size_t)b * 256 * SS;
    ushort* pw = ps + wave * (8 * 16 * PROW);

    for (int ti = ts * 5; ti < ts * 5 + 5; ++ti) {
        const int t0 = ti * 32;
        __syncthreads();
        {   // K tile [32 t][256 c]
            const int row = tid >> 3, ce = (tid & 7) * 32;
            const int t = t0 + row;
            const ushort* src = ktb + (size_t)t * 256 + ce;
            #pragma unroll
            for (int j = 0; j < 4; ++j) {
                s16x8 v = (t < SS) ? *(const s16x8*)(src + 8 * j) : Z8;
                *(s16x8*)&ks[row * KROW + ce + 8 * j] = v;
            }
        }
        {   // V tile [256 c][32 t]
            const ushort* src = vb + (size_t)tid * SS + t0;
            #pragma unroll
            for (int j = 0; j < 4; ++j) {
                s16x8 v = (t0 + 8 * j < SS) ? *(const s16x8*)(src + 8 * j) : Z8;
                *(s16x8*)&vs[tid * VROW + 8 * j] = v;
            }
        }
        __syncthreads();

        // logits (q pre-scaled by log2(e)/sqrt(dk) -> exp2 softmax)
        f32x4 lacc[8][2];
        #pragma unroll
        for (int n = 0; n < 8; ++n) {
            #pragma unroll
            for (int h = 0; h < 2; ++h) {
                s16x8 bk = *(const s16x8*)&ks[(h * 16 + lm) * KROW + n * 32 + 8 * lg];
                lacc[n][h] = __builtin_amdgcn_mfma_f32_16x16x32_bf16(qf[n], bk, Z4, 0, 0, 0);
            }
        }

        // head-axis softmax, lane-local; P -> LDS (bf16)
        #pragma unroll
        for (int h = 0; h < 2; ++h) {
            #pragma unroll
            for (int r = 0; r < 4; ++r) {
                float m = lacc[0][h][r];
                #pragma unroll
                for (int n = 1; n < 8; ++n) m = fmaxf(m, lacc[n][h][r]);
                float e[8]; float sum = 0.f;
                #pragma unroll
                for (int n = 0; n < 8; ++n) { e[n] = exp2f(lacc[n][h][r] - m); sum += e[n]; }
                float inv;
                asm("v_rcp_f32 %0, %1" : "=v"(inv) : "v"(sum));
                const int srow = 4 * lg + r, tcol = h * 16 + lm;
                #pragma unroll
                for (int n = 0; n < 8; ++n)
                    pw[(n * 16 + srow) * PROW + tcol] = f2bf(e[n] * inv);
            }
        }

        // PV
        #pragma unroll
        for (int n = 0; n < 8; ++n) {
            s16x8 aw = *(const s16x8*)&pw[(n * 16 + lm) * PROW + 8 * lg];
            #pragma unroll
            for (int dh = 0; dh < 2; ++dh) {
                s16x8 bv8 = *(const s16x8*)&vs[(n * 32 + dh * 16 + lm) * VROW + 8 * lg];
                oacc[n][dh] = __builtin_amdgcn_mfma_f32_16x16x32_bf16(aw, bv8, oacc[n][dh], 0, 0, 0);
            }
        }
    }

    if (valid) {
        ushort* part = (ts < 4) ? (pb + (size_t)ts * NQE) : p4;
        const size_t base = (size_t)b * 200704 + (size_t)s0 * 32 + lg * 128 + lm;
        #pragma unroll
        for (int n = 0; n < 8; ++n) {
            const size_t hb = base + n * 25088;
            #pragma unroll
            for (int dh = 0; dh < 2; ++dh)
                #pragma unroll
                for (int r = 0; r < 4; ++r)
                    part[hb + r * 32 + dh * 16] = f2bf(oacc[n][dh][r]);
        }
    }
}

// ---------------- sum 5 partials [b][c2][p] + transpose -> sumb[b][p][256] ----------------
__global__ __launch_bounds__(256) void sum5t(const ushort* __restrict__ a0,
                                             const ushort* __restrict__ a1,
                                             const ushort* __restrict__ a2,
                                             const ushort* __restrict__ a3,
                                             const ushort* __restrict__ a4,
                                             ushort* __restrict__ outb) {
    __shared__ ushort Ts[64][72];
    const int tid = threadIdx.x;
    const int p0 = blockIdx.x * 64, c0 = blockIdx.y * 64, b = blockIdx.z;
    const int cr = tid >> 2, ch = (tid & 3) * 16;
    if (p0 + ch < SS) {
        const size_t off = ((size_t)b * 256 + c0 + cr) * SS + p0 + ch;
        #pragma unroll
        for (int jj = 0; jj < 2; ++jj) {
            s16x8 v0 = *(const s16x8*)(a0 + off + 8 * jj);
            s16x8 v1 = *(const s16x8*)(a1 + off + 8 * jj);
            s16x8 v2 = *(const s16x8*)(a2 + off + 8 * jj);
            s16x8 v3 = *(const s16x8*)(a3 + off + 8 * jj);
            s16x8 v4 = *(const s16x8*)(a4 + off + 8 * jj);
            #pragma unroll
            for (int j = 0; j < 8; ++j) {
                float s = bf2f((ushort)v0[j]) + bf2f((ushort)v1[j]) + bf2f((ushort)v2[j])
                        + bf2f((ushort)v3[j]) + bf2f((ushort)v4[j]);
                Ts[ch + jj * 8 + j][cr] = f2bf(s);
            }
        }
    } else {
        #pragma unroll
        for (int j = 0; j < 16; ++j) Ts[ch + j][cr] = 0;
    }
    __syncthreads();
    const int pr = tid >> 2, cc = (tid & 3) * 16;
    if (p0 + pr < SS) {
        ushort* dst = outb + ((size_t)b * SS + p0 + pr) * 256 + c0 + cc;
        *(s16x8*)dst       = *(const s16x8*)&Ts[pr][cc];
        *(s16x8*)(dst + 8) = *(const s16x8*)&Ts[pr][cc + 8];
    }
}

extern "C" void kernel_launch(void* const* d_in, const int* in_sizes, int n_in,
                              void* d_out, int out_size, void* d_ws, size_t ws_size,
                              hipStream_t stream) {
    const float* inputs    = (const float*)d_in[0];
    const float* inputs_st = (const float*)d_in[1];
    const float* Wq        = (const float*)d_in[2];
    const float* bq        = (const float*)d_in[3];
    const float* Wkv       = (const float*)d_in[4];
    const float* bkv       = (const float*)d_in[5];
    const float* Wo        = (const float*)d_in[6];
    const float* bo        = (const float*)d_in[7];
    float* out = (float*)d_out;

    // ws map (ushort units), 8 slots of NQE. Total 25,690,112 B.
    ushort* W     = (ushort*)d_ws;
    ushort* xt_q  = W;                      // slots 0-1 (later partials 0,1)
    ushort* xt_kv = W + 2 * (size_t)NQE;    // slots 2-3 (later partials 2,3)
    ushort* qt    = W + 4 * (size_t)NQE;    // slot 4 (later summed attn)
    ushort* kt    = W + 5 * (size_t)NQE;
    ushort* vv    = W + 6 * (size_t)NQE;
    ushort* p4    = W + 7 * (size_t)NQE;
    ushort* sumb  = qt;

    const float qscale = (float)(1.4426950408889634 / 5.656854249492380195); // log2(e)/sqrt(32)

    transpose_cvt<<<dim3(13, 8, 8), dim3(256), 0, stream>>>(inputs, xt_q);
    transpose_cvt<<<dim3(13, 8, 8), dim3(256), 0, stream>>>(inputs_st, xt_kv);
    gemm_qk<<<dim3(7, 2, 8), dim3(256), 0, stream>>>(xt_q, Wq, bq, qt, qscale);
    gemm_qk<<<dim3(7, 2, 8), dim3(256), 0, stream>>>(xt_kv, Wkv, bkv, kt, 1.0f);
    gemm_pn<512, 256, false><<<dim3(2, 7, 8), dim3(256), 0, stream>>>(xt_kv, Wkv + 256 * 512, bkv + 256, vv);
    attn_mfma<<<dim3(65, 8), dim3(256), 0, stream>>>(qt, kt, vv, W, p4);
    sum5t<<<dim3(13, 4, 8), dim3(256), 0, stream>>>(W, W + (size_t)NQE, W + 2 * (size_t)NQE,
                                                    W + 3 * (size_t)NQE, p4, sumb);
    gemm_pn<256, 512, true><<<dim3(4, 7, 8), dim3(256), 0, stream>>>(sumb, Wo, bo, out);
}

// Round 6
// 133.491 us; speedup vs baseline: 14.1794x; 1.1372x over previous
//
#include <hip/hip_runtime.h>

#define SS 784
#define NQE 1605632          // 8*784*256 (elements of one bf16 buffer)

typedef float f32x4 __attribute__((ext_vector_type(4)));
typedef short s16x8 __attribute__((ext_vector_type(8)));

__device__ inline ushort f2bf(float f) {
    union { float f; unsigned u; } v; v.f = f;
    return (ushort)((v.u + 0x7fff + ((v.u >> 16) & 1)) >> 16);
}
__device__ inline float bf2f(ushort h) {
    union { unsigned u; float f; } v; v.u = ((unsigned)h) << 16;
    return v.f;
}
__device__ inline unsigned cvt_pk_bf16(float lo, float hi) {
    unsigned r;
    asm("v_cvt_pk_bf16_f32 %0, %1, %2" : "=v"(r) : "v"(lo), "v"(hi));
    return r;
}

// ---------------- transpose + f32->bf16: X[b][c][p] -> Xt[b][p][c] ----------------
__global__ __launch_bounds__(256) void transpose_cvt(const float* __restrict__ X,
                                                     ushort* __restrict__ Xt) {
    __shared__ ushort Ts[64][72];
    const int tid = threadIdx.x;
    const int p0 = blockIdx.x * 64, c0 = blockIdx.y * 64, b = blockIdx.z;
    const int cr = tid >> 2, ch = (tid & 3) * 16;
    if (p0 + ch < SS) {
        const float* src = X + ((size_t)b * 512 + c0 + cr) * SS + p0 + ch;
        #pragma unroll
        for (int jj = 0; jj < 4; ++jj) {
            float4 v = *(const float4*)(src + jj * 4);
            Ts[ch + jj * 4 + 0][cr] = f2bf(v.x);
            Ts[ch + jj * 4 + 1][cr] = f2bf(v.y);
            Ts[ch + jj * 4 + 2][cr] = f2bf(v.z);
            Ts[ch + jj * 4 + 3][cr] = f2bf(v.w);
        }
    } else {
        #pragma unroll
        for (int j = 0; j < 16; ++j) Ts[ch + j][cr] = 0;
    }
    __syncthreads();
    const int pr = tid >> 2, cc = (tid & 3) * 16;
    if (p0 + pr < SS) {
        ushort* dst = Xt + ((size_t)b * SS + p0 + pr) * 512 + c0 + cc;
        *(s16x8*)dst       = *(const s16x8*)&Ts[pr][cc];
        *(s16x8*)(dst + 8) = *(const s16x8*)&Ts[pr][cc + 8];
    }
}

// ---------------- Q/K projection: D[o][p] = W[o][:]·Xt[p][:] ; out bf16 [b][p][o] ----------------
__global__ __launch_bounds__(256) void gemm_qk(const ushort* __restrict__ Xt,
                                               const float* __restrict__ Wg,
                                               const float* __restrict__ bias,
                                               ushort* __restrict__ outT,      // [b][p][256]
                                               float scale) {
    __shared__ ushort As[128 * 40];
    __shared__ ushort Bs[128 * 40];
    const int tid = threadIdx.x;
    const int lane = tid & 63, wave = tid >> 6;
    const int wm = wave >> 1, wn = wave & 1;
    const int lg = lane >> 4, lm = lane & 15;
    const int p0 = blockIdx.x * 128;
    const int o0 = blockIdx.y * 128;
    const int b  = blockIdx.z;
    const int srow = tid >> 1, shalf = (tid & 1) * 16;

    const f32x4 Z4 = {0.f, 0.f, 0.f, 0.f};
    const s16x8 Z8 = {0, 0, 0, 0, 0, 0, 0, 0};
    f32x4 acc[4][4];
    #pragma unroll
    for (int m = 0; m < 4; ++m)
        #pragma unroll
        for (int n = 0; n < 4; ++n) acc[m][n] = Z4;

    for (int c0 = 0; c0 < 512; c0 += 32) {
        __syncthreads();
        {   // A: W f32 -> bf16
            const float* src = Wg + (size_t)(o0 + srow) * 512 + c0 + shalf;
            ushort tmp[16];
            #pragma unroll
            for (int jj = 0; jj < 4; ++jj) {
                float4 v = *(const float4*)(src + jj * 4);
                tmp[jj * 4 + 0] = f2bf(v.x); tmp[jj * 4 + 1] = f2bf(v.y);
                tmp[jj * 4 + 2] = f2bf(v.z); tmp[jj * 4 + 3] = f2bf(v.w);
            }
            *(s16x8*)&As[srow * 40 + shalf]     = *(s16x8*)&tmp[0];
            *(s16x8*)&As[srow * 40 + shalf + 8] = *(s16x8*)&tmp[8];
        }
        {   // B: Xt bf16 copy
            int p = p0 + srow;
            s16x8 v0 = Z8, v1 = Z8;
            if (p < SS) {
                const ushort* src = Xt + ((size_t)b * SS + p) * 512 + c0 + shalf;
                v0 = *(const s16x8*)src;
                v1 = *(const s16x8*)(src + 8);
            }
            *(s16x8*)&Bs[srow * 40 + shalf]     = v0;
            *(s16x8*)&Bs[srow * 40 + shalf + 8] = v1;
        }
        __syncthreads();
        s16x8 af[4], bf[4];
        #pragma unroll
        for (int m = 0; m < 4; ++m) af[m] = *(const s16x8*)&As[(wm * 64 + m * 16 + lm) * 40 + 8 * lg];
        #pragma unroll
        for (int n = 0; n < 4; ++n) bf[n] = *(const s16x8*)&Bs[(wn * 64 + n * 16 + lm) * 40 + 8 * lg];
        #pragma unroll
        for (int m = 0; m < 4; ++m)
            #pragma unroll
            for (int n = 0; n < 4; ++n)
                acc[m][n] = __builtin_amdgcn_mfma_f32_16x16x32_bf16(af[m], bf[n], acc[m][n], 0, 0, 0);
    }

    #pragma unroll
    for (int m = 0; m < 4; ++m) {
        const int o = o0 + wm * 64 + m * 16 + 4 * lg;
        float bv[4];
        #pragma unroll
        for (int r = 0; r < 4; ++r) bv[r] = bias[o + r];
        #pragma unroll
        for (int n = 0; n < 4; ++n) {
            const int p = p0 + wn * 64 + n * 16 + lm;
            if (p < SS) {
                ushort4 w;
                w.x = f2bf((acc[m][n][0] + bv[0]) * scale);
                w.y = f2bf((acc[m][n][1] + bv[1]) * scale);
                w.z = f2bf((acc[m][n][2] + bv[2]) * scale);
                w.w = f2bf((acc[m][n][3] + bv[3]) * scale);
                *(ushort4*)&outT[((size_t)b * SS + p) * 256 + o] = w;
            }
        }
    }
}

// ---------------- generic: D[p][o] = A[p][:]·W[o][:] ----------------
template<int KD, int NCH, bool OUTF32>
__global__ __launch_bounds__(256) void gemm_pn(const ushort* __restrict__ A,
                                               const float* __restrict__ Wg,
                                               const float* __restrict__ bias,
                                               void* __restrict__ outp) {
    __shared__ ushort As[128 * 40];
    __shared__ ushort Bs[128 * 40];
    const int tid = threadIdx.x;
    const int lane = tid & 63, wave = tid >> 6;
    const int wm = wave >> 1, wn = wave & 1;
    const int lg = lane >> 4, lm = lane & 15;
    const int o0 = blockIdx.x * 128;
    const int p0 = blockIdx.y * 128;
    const int b  = blockIdx.z;
    const int srow = tid >> 1, shalf = (tid & 1) * 16;

    const f32x4 Z4 = {0.f, 0.f, 0.f, 0.f};
    const s16x8 Z8 = {0, 0, 0, 0, 0, 0, 0, 0};
    f32x4 acc[4][4];
    #pragma unroll
    for (int m = 0; m < 4; ++m)
        #pragma unroll
        for (int n = 0; n < 4; ++n) acc[m][n] = Z4;

    for (int c0 = 0; c0 < KD; c0 += 32) {
        __syncthreads();
        {
            int p = p0 + srow;
            s16x8 v0 = Z8, v1 = Z8;
            if (p < SS) {
                const ushort* src = A + ((size_t)b * SS + p) * KD + c0 + shalf;
                v0 = *(const s16x8*)src;
                v1 = *(const s16x8*)(src + 8);
            }
            *(s16x8*)&As[srow * 40 + shalf]     = v0;
            *(s16x8*)&As[srow * 40 + shalf + 8] = v1;
        }
        {
            const float* src = Wg + (size_t)(o0 + srow) * KD + c0 + shalf;
            ushort tmp[16];
            #pragma unroll
            for (int jj = 0; jj < 4; ++jj) {
                float4 v = *(const float4*)(src + jj * 4);
                tmp[jj * 4 + 0] = f2bf(v.x); tmp[jj * 4 + 1] = f2bf(v.y);
                tmp[jj * 4 + 2] = f2bf(v.z); tmp[jj * 4 + 3] = f2bf(v.w);
            }
            *(s16x8*)&Bs[srow * 40 + shalf]     = *(s16x8*)&tmp[0];
            *(s16x8*)&Bs[srow * 40 + shalf + 8] = *(s16x8*)&tmp[8];
        }
        __syncthreads();
        s16x8 af[4], bf[4];
        #pragma unroll
        for (int m = 0; m < 4; ++m) af[m] = *(const s16x8*)&As[(wm * 64 + m * 16 + lm) * 40 + 8 * lg];
        #pragma unroll
        for (int n = 0; n < 4; ++n) bf[n] = *(const s16x8*)&Bs[(wn * 64 + n * 16 + lm) * 40 + 8 * lg];
        #pragma unroll
        for (int m = 0; m < 4; ++m)
            #pragma unroll
            for (int n = 0; n < 4; ++n)
                acc[m][n] = __builtin_amdgcn_mfma_f32_16x16x32_bf16(af[m], bf[n], acc[m][n], 0, 0, 0);
    }

    #pragma unroll
    for (int n = 0; n < 4; ++n) {
        const int o = o0 + wn * 64 + n * 16 + lm;
        const float bv = bias[o];
        #pragma unroll
        for (int m = 0; m < 4; ++m) {
            const int p = p0 + wm * 64 + m * 16 + 4 * lg;
            if (p < SS) {
                if (OUTF32) {
                    f32x4 v;
                    #pragma unroll
                    for (int r = 0; r < 4; ++r) v[r] = acc[m][n][r] + bv;
                    *(f32x4*)&((float*)outp)[((size_t)b * NCH + o) * SS + p] = v;
                } else {
                    ushort4 w;
                    w.x = f2bf(acc[m][n][0] + bv);
                    w.y = f2bf(acc[m][n][1] + bv);
                    w.z = f2bf(acc[m][n][2] + bv);
                    w.w = f2bf(acc[m][n][3] + bv);
                    *(ushort4*)&((ushort*)outp)[((size_t)b * NCH + o) * SS + p] = w;
                }
            }
        }
    }
}

// ---------------- fused MFMA attention: swapped QK^T, small ping-pong P-LDS ----------------
// S^T = mfma(A=K, B=Q): lane (lg,lm) holds S^T[t = h*16+4lg+r][s = lm] (m89 C-layout).
// Head softmax over n is register-local. P^T packed to bf16 -> per-head LDS bounce:
// write rows [s=lm][t=h*16+4lg..+3] as b64, read B-fragment [k=8lg+j][col=lm] as b128.
// PV: O^T = mfma(A=V^T, B=P^T) (16x16x32, verified). O^T lane layout: d = dh*16+4lg+r,
// s = lm -> f = s*32+d contiguous in r -> 8B stores.
#define KROW 264   // 528B rows (33*16B, odd)
#define VROW 40    // 80B rows
#define PROW 40    // 80B rows

__global__ __launch_bounds__(256, 3) void attn_mfma(const ushort* __restrict__ qt,
                                                    const ushort* __restrict__ kt,
                                                    const ushort* __restrict__ vv,
                                                    ushort* __restrict__ pb,
                                                    ushort* __restrict__ p4) {
    __shared__ ushort ks[32 * KROW];          // 16896 B
    __shared__ ushort vs[256 * VROW];         // 20480 B
    __shared__ ushort pls[4 * 2 * 16 * PROW]; // 10240 B ping-pong P tiles (per wave x2)
    const int tid  = threadIdx.x;
    const int lane = tid & 63;
    const int wave = tid >> 6;
    const int b     = blockIdx.y;
    const int stile = blockIdx.x / 5;
    const int ts    = blockIdx.x % 5;
    int strip = stile * 4 + wave;
    const bool valid = (strip < 49);
    if (!valid) strip = 48;
    const int s0 = strip * 16;

    const int lg = lane >> 4, lm = lane & 15;
    const s16x8 Z8 = {0, 0, 0, 0, 0, 0, 0, 0};
    const f32x4 Z4 = {0.f, 0.f, 0.f, 0.f};

    // Q fragment per head (B-operand of S^T mfma): lane holds Q[s0+lm][n*32 + 8lg + j]
    s16x8 qf[8];
    const ushort* qbase = qt + ((size_t)b * SS + s0 + lm) * 256 + 8 * lg;
    #pragma unroll
    for (int n = 0; n < 8; ++n) qf[n] = *(const s16x8*)(qbase + n * 32);

    f32x4 oacc[8][2];
    #pragma unroll
    for (int n = 0; n < 8; ++n) { oacc[n][0] = Z4; oacc[n][1] = Z4; }

    const ushort* ktb = kt + (size_t)b * SS * 256;
    const ushort* vb  = vv + (size_t)b * 256 * SS;
    ushort* pbase = pls + wave * (2 * 16 * PROW);

    for (int ti = ts * 5; ti < ts * 5 + 5; ++ti) {
        const int t0 = ti * 32;
        __syncthreads();
        {   // K tile [32 t][256 c]
            const int row = tid >> 3, ce = (tid & 7) * 32;
            const int t = t0 + row;
            const ushort* src = ktb + (size_t)t * 256 + ce;
            #pragma unroll
            for (int j = 0; j < 4; ++j) {
                s16x8 v = (t < SS) ? *(const s16x8*)(src + 8 * j) : Z8;
                *(s16x8*)&ks[row * KROW + ce + 8 * j] = v;
            }
        }
        {   // V tile [256 c][32 t]
            const ushort* src = vb + (size_t)tid * SS + t0;
            #pragma unroll
            for (int j = 0; j < 4; ++j) {
                s16x8 v = (t0 + 8 * j < SS) ? *(const s16x8*)(src + 8 * j) : Z8;
                *(s16x8*)&vs[tid * VROW + 8 * j] = v;
            }
        }
        __syncthreads();

        // S^T logits + head softmax (max-free, exp2 domain; logits small by construction)
        unsigned pku[2][8][2];
        #pragma unroll
        for (int h = 0; h < 2; ++h) {
            f32x4 lacc[8];
            #pragma unroll
            for (int n = 0; n < 8; ++n) {
                s16x8 ak = *(const s16x8*)&ks[(h * 16 + lm) * KROW + n * 32 + 8 * lg];
                lacc[n] = __builtin_amdgcn_mfma_f32_16x16x32_bf16(ak, qf[n], Z4, 0, 0, 0);
            }
            #pragma unroll
            for (int r = 0; r < 4; ++r) {
                float e[8]; float sum = 0.f;
                #pragma unroll
                for (int n = 0; n < 8; ++n) { e[n] = exp2f(lacc[n][r]); sum += e[n]; }
                float inv;
                asm("v_rcp_f32 %0, %1" : "=v"(inv) : "v"(sum));
                #pragma unroll
                for (int n = 0; n < 8; ++n) lacc[n][r] = e[n] * inv;
            }
            #pragma unroll
            for (int n = 0; n < 8; ++n) {
                pku[h][n][0] = cvt_pk_bf16(lacc[n][0], lacc[n][1]);
                pku[h][n][1] = cvt_pk_bf16(lacc[n][2], lacc[n][3]);
            }
        }

        // PV per head via tiny LDS bounce (wave-private ping-pong; per-lane address
        // overlap between write cols [4lg..4lg+3] and read cols [8lg..8lg+7] forces
        // compiler lgkmcnt ordering -> no barrier needed)
        #pragma unroll
        for (int n = 0; n < 8; ++n) {
            ushort* pw = pbase + (n & 1) * (16 * PROW);
            uint2 w0; w0.x = pku[0][n][0]; w0.y = pku[0][n][1];
            *(uint2*)&pw[lm * PROW + 4 * lg] = w0;
            uint2 w1; w1.x = pku[1][n][0]; w1.y = pku[1][n][1];
            *(uint2*)&pw[lm * PROW + 16 + 4 * lg] = w1;
            s16x8 pbf = *(const s16x8*)&pw[lm * PROW + 8 * lg];
            #pragma unroll
            for (int dh = 0; dh < 2; ++dh) {
                s16x8 va = *(const s16x8*)&vs[(n * 32 + dh * 16 + lm) * VROW + 8 * lg];
                oacc[n][dh] = __builtin_amdgcn_mfma_f32_16x16x32_bf16(va, pbf, oacc[n][dh], 0, 0, 0);
            }
        }
    }

    if (valid) {
        ushort* part = (ts < 4) ? (pb + (size_t)ts * NQE) : p4;
        // O^T: s = lm, d = dh*16 + 4lg + r -> f = lm*32 + dh*16 + 4lg + r (r contiguous)
        const size_t base = (size_t)b * 200704 + (size_t)s0 * 32 + lm * 32 + 4 * lg;
        #pragma unroll
        for (int n = 0; n < 8; ++n) {
            #pragma unroll
            for (int dh = 0; dh < 2; ++dh) {
                uint2 w;
                w.x = cvt_pk_bf16(oacc[n][dh][0], oacc[n][dh][1]);
                w.y = cvt_pk_bf16(oacc[n][dh][2], oacc[n][dh][3]);
                *(uint2*)&part[base + n * 25088 + dh * 16] = w;
            }
        }
    }
}

// ---------------- sum 5 partials [b][c2][p] + transpose -> sumb[b][p][256] ----------------
__global__ __launch_bounds__(256) void sum5t(const ushort* __restrict__ a0,
                                             const ushort* __restrict__ a1,
                                             const ushort* __restrict__ a2,
                                             const ushort* __restrict__ a3,
                                             const ushort* __restrict__ a4,
                                             ushort* __restrict__ outb) {
    __shared__ ushort Ts[64][72];
    const int tid = threadIdx.x;
    const int p0 = blockIdx.x * 64, c0 = blockIdx.y * 64, b = blockIdx.z;
    const int cr = tid >> 2, ch = (tid & 3) * 16;
    if (p0 + ch < SS) {
        const size_t off = ((size_t)b * 256 + c0 + cr) * SS + p0 + ch;
        #pragma unroll
        for (int jj = 0; jj < 2; ++jj) {
            s16x8 v0 = *(const s16x8*)(a0 + off + 8 * jj);
            s16x8 v1 = *(const s16x8*)(a1 + off + 8 * jj);
            s16x8 v2 = *(const s16x8*)(a2 + off + 8 * jj);
            s16x8 v3 = *(const s16x8*)(a3 + off + 8 * jj);
            s16x8 v4 = *(const s16x8*)(a4 + off + 8 * jj);
            #pragma unroll
            for (int j = 0; j < 8; ++j) {
                float s = bf2f((ushort)v0[j]) + bf2f((ushort)v1[j]) + bf2f((ushort)v2[j])
                        + bf2f((ushort)v3[j]) + bf2f((ushort)v4[j]);
                Ts[ch + jj * 8 + j][cr] = f2bf(s);
            }
        }
    } else {
        #pragma unroll
        for (int j = 0; j < 16; ++j) Ts[ch + j][cr] = 0;
    }
    __syncthreads();
    const int pr = tid >> 2, cc = (tid & 3) * 16;
    if (p0 + pr < SS) {
        ushort* dst = outb + ((size_t)b * SS + p0 + pr) * 256 + c0 + cc;
        *(s16x8*)dst       = *(const s16x8*)&Ts[pr][cc];
        *(s16x8*)(dst + 8) = *(const s16x8*)&Ts[pr][cc + 8];
    }
}

extern "C" void kernel_launch(void* const* d_in, const int* in_sizes, int n_in,
                              void* d_out, int out_size, void* d_ws, size_t ws_size,
                              hipStream_t stream) {
    const float* inputs    = (const float*)d_in[0];
    const float* inputs_st = (const float*)d_in[1];
    const float* Wq        = (const float*)d_in[2];
    const float* bq        = (const float*)d_in[3];
    const float* Wkv       = (const float*)d_in[4];
    const float* bkv       = (const float*)d_in[5];
    const float* Wo        = (const float*)d_in[6];
    const float* bo        = (const float*)d_in[7];
    float* out = (float*)d_out;

    ushort* W     = (ushort*)d_ws;
    ushort* xt_q  = W;                      // slots 0-1 (later partials 0,1)
    ushort* xt_kv = W + 2 * (size_t)NQE;    // slots 2-3 (later partials 2,3)
    ushort* qt    = W + 4 * (size_t)NQE;    // slot 4 (later summed attn)
    ushort* kt    = W + 5 * (size_t)NQE;
    ushort* vv    = W + 6 * (size_t)NQE;
    ushort* p4    = W + 7 * (size_t)NQE;
    ushort* sumb  = qt;

    const float qscale = (float)(1.4426950408889634 / 5.656854249492380195); // log2(e)/sqrt(32)

    transpose_cvt<<<dim3(13, 8, 8), dim3(256), 0, stream>>>(inputs, xt_q);
    transpose_cvt<<<dim3(13, 8, 8), dim3(256), 0, stream>>>(inputs_st, xt_kv);
    gemm_qk<<<dim3(7, 2, 8), dim3(256), 0, stream>>>(xt_q, Wq, bq, qt, qscale);
    gemm_qk<<<dim3(7, 2, 8), dim3(256), 0, stream>>>(xt_kv, Wkv, bkv, kt, 1.0f);
    gemm_pn<512, 256, false><<<dim3(2, 7, 8), dim3(256), 0, stream>>>(xt_kv, Wkv + 256 * 512, bkv + 256, vv);
    attn_mfma<<<dim3(65, 8), dim3(256), 0, stream>>>(qt, kt, vv, W, p4);
    sum5t<<<dim3(13, 4, 8), dim3(256), 0, stream>>>(W, W + (size_t)NQE, W + 2 * (size_t)NQE,
                                                    W + 3 * (size_t)NQE, p4, sumb);
    gemm_pn<256, 512, true><<<dim3(4, 7, 8), dim3(256), 0, stream>>>(sumb, Wo, bo, out);
}

// Round 7
// 91.845 us; speedup vs baseline: 20.6087x; 1.4534x over previous
//
#include <hip/hip_runtime.h>

#define SS 784
#define NQE 1605632          // 8*784*256 (elements of one bf16 buffer)

typedef float f32x4 __attribute__((ext_vector_type(4)));
typedef short s16x8 __attribute__((ext_vector_type(8)));

__device__ inline ushort f2bf(float f) {
    union { float f; unsigned u; } v; v.f = f;
    return (ushort)((v.u + 0x7fff + ((v.u >> 16) & 1)) >> 16);
}
__device__ inline float bf2f(ushort h) {
    union { unsigned u; float f; } v; v.u = ((unsigned)h) << 16;
    return v.f;
}
__device__ inline unsigned cvt_pk_bf16(float lo, float hi) {
    unsigned r;
    asm("v_cvt_pk_bf16_f32 %0, %1, %2" : "=v"(r) : "v"(lo), "v"(hi));
    return r;
}

// ---------------- transpose + f32->bf16 for BOTH inputs: X[b][c][p] -> Xt[b][p][c] -------------
__global__ __launch_bounds__(256) void transpose_cvt2(const float* __restrict__ X0,
                                                      const float* __restrict__ X1,
                                                      ushort* __restrict__ Xt0,
                                                      ushort* __restrict__ Xt1) {
    __shared__ ushort Ts[64][72];
    const int tid = threadIdx.x;
    const int p0 = blockIdx.x * 64, c0 = blockIdx.y * 64;
    const int z  = blockIdx.z;              // 0..15: [0..7]=input0 b, [8..15]=input1 b
    const int b  = z & 7;
    const float*  X  = (z < 8) ? X0 : X1;
    ushort*       Xt = (z < 8) ? Xt0 : Xt1;
    const int cr = tid >> 2, ch = (tid & 3) * 16;
    if (p0 + ch < SS) {
        const float* src = X + ((size_t)b * 512 + c0 + cr) * SS + p0 + ch;
        #pragma unroll
        for (int jj = 0; jj < 4; ++jj) {
            float4 v = *(const float4*)(src + jj * 4);
            Ts[ch + jj * 4 + 0][cr] = f2bf(v.x);
            Ts[ch + jj * 4 + 1][cr] = f2bf(v.y);
            Ts[ch + jj * 4 + 2][cr] = f2bf(v.z);
            Ts[ch + jj * 4 + 3][cr] = f2bf(v.w);
        }
    } else {
        #pragma unroll
        for (int j = 0; j < 16; ++j) Ts[ch + j][cr] = 0;
    }
    __syncthreads();
    const int pr = tid >> 2, cc = (tid & 3) * 16;
    if (p0 + pr < SS) {
        ushort* dst = Xt + ((size_t)b * SS + p0 + pr) * 512 + c0 + cc;
        *(s16x8*)dst       = *(const s16x8*)&Ts[pr][cc];
        *(s16x8*)(dst + 8) = *(const s16x8*)&Ts[pr][cc + 8];
    }
}

// ---------------- merged Q/K/V projection (one launch, 336 blocks, b = id%8) ----------------
// oy 0-1: Q -> qt[b][p][o] (scaled) ; oy 2-3: K -> kt[b][p][o] ; oy 4-5: V -> vv[b][c][p]
__global__ __launch_bounds__(256) void gemm_qkv(const ushort* __restrict__ xt_q,
                                                const ushort* __restrict__ xt_kv,
                                                const float* __restrict__ Wq,
                                                const float* __restrict__ bq,
                                                const float* __restrict__ Wkv,
                                                const float* __restrict__ bkv,
                                                ushort* __restrict__ qt,
                                                ushort* __restrict__ kt,
                                                ushort* __restrict__ vv,
                                                float qscale) {
    __shared__ ushort As[128 * 40];   // W rows (o)
    __shared__ ushort Bs[128 * 40];   // Xt rows (p)
    const int id  = blockIdx.x;       // 336 = 8b * (7p * 6o); id%8=b -> XCD=b
    const int b   = id & 7;
    const int sub = id >> 3;
    const int oy  = sub % 6;
    const int p0  = (sub / 6) * 128;
    const int mode = (oy < 2) ? 0 : (oy < 4 ? 1 : 2);
    const ushort* Xt  = (mode == 0) ? xt_q : xt_kv;
    const float* Wg   = (mode == 0) ? Wq : Wkv;
    const float* bias = (mode == 0) ? bq : bkv;
    const int o0w = (mode == 0) ? oy * 128 : (oy - 2) * 128;   // row into Wg/bias

    const int tid = threadIdx.x;
    const int lane = tid & 63, wave = tid >> 6;
    const int wm = wave >> 1, wn = wave & 1;
    const int lg = lane >> 4, lm = lane & 15;
    const int srow = tid >> 1, shalf = (tid & 1) * 16;

    const f32x4 Z4 = {0.f, 0.f, 0.f, 0.f};
    const s16x8 Z8 = {0, 0, 0, 0, 0, 0, 0, 0};
    f32x4 acc[4][4];
    #pragma unroll
    for (int m = 0; m < 4; ++m)
        #pragma unroll
        for (int n = 0; n < 4; ++n) acc[m][n] = Z4;

    for (int c0 = 0; c0 < 512; c0 += 32) {
        __syncthreads();
        {   // A: W f32 -> bf16
            const float* src = Wg + (size_t)(o0w + srow) * 512 + c0 + shalf;
            ushort tmp[16];
            #pragma unroll
            for (int jj = 0; jj < 4; ++jj) {
                float4 v = *(const float4*)(src + jj * 4);
                tmp[jj * 4 + 0] = f2bf(v.x); tmp[jj * 4 + 1] = f2bf(v.y);
                tmp[jj * 4 + 2] = f2bf(v.z); tmp[jj * 4 + 3] = f2bf(v.w);
            }
            *(s16x8*)&As[srow * 40 + shalf]     = *(s16x8*)&tmp[0];
            *(s16x8*)&As[srow * 40 + shalf + 8] = *(s16x8*)&tmp[8];
        }
        {   // B: Xt bf16
            int p = p0 + srow;
            s16x8 v0 = Z8, v1 = Z8;
            if (p < SS) {
                const ushort* src = Xt + ((size_t)b * SS + p) * 512 + c0 + shalf;
                v0 = *(const s16x8*)src;
                v1 = *(const s16x8*)(src + 8);
            }
            *(s16x8*)&Bs[srow * 40 + shalf]     = v0;
            *(s16x8*)&Bs[srow * 40 + shalf + 8] = v1;
        }
        __syncthreads();
        s16x8 af[4], bf[4];
        #pragma unroll
        for (int m = 0; m < 4; ++m) af[m] = *(const s16x8*)&As[(wm * 64 + m * 16 + lm) * 40 + 8 * lg];
        #pragma unroll
        for (int n = 0; n < 4; ++n) bf[n] = *(const s16x8*)&Bs[(wn * 64 + n * 16 + lm) * 40 + 8 * lg];
        #pragma unroll
        for (int m = 0; m < 4; ++m)
            #pragma unroll
            for (int n = 0; n < 4; ++n)
                acc[m][n] = __builtin_amdgcn_mfma_f32_16x16x32_bf16(af[m], bf[n], acc[m][n], 0, 0, 0);
    }

    if (mode < 2) {
        // transposed write: out[b][p][256] at channel o (D: row=o=4lg+r, col=p=lm)
        ushort* outT = (mode == 0) ? qt : kt;
        const float scale = (mode == 0) ? qscale : 1.0f;
        #pragma unroll
        for (int m = 0; m < 4; ++m) {
            const int o = o0w + wm * 64 + m * 16 + 4 * lg;
            float bv[4];
            #pragma unroll
            for (int r = 0; r < 4; ++r) bv[r] = bias[o + r];
            #pragma unroll
            for (int n = 0; n < 4; ++n) {
                const int p = p0 + wn * 64 + n * 16 + lm;
                if (p < SS) {
                    ushort4 w;
                    w.x = f2bf((acc[m][n][0] + bv[0]) * scale);
                    w.y = f2bf((acc[m][n][1] + bv[1]) * scale);
                    w.z = f2bf((acc[m][n][2] + bv[2]) * scale);
                    w.w = f2bf((acc[m][n][3] + bv[3]) * scale);
                    *(ushort4*)&outT[((size_t)b * SS + p) * 256 + o] = w;
                }
            }
        }
    } else {
        // V: vv[b][c][p], c = o0w-256 + ... ; 2B stores, block covers full 128x128 region
        #pragma unroll
        for (int m = 0; m < 4; ++m) {
            const int ob = o0w + wm * 64 + m * 16 + 4 * lg;
            float bv[4];
            #pragma unroll
            for (int r = 0; r < 4; ++r) bv[r] = bias[ob + r];
            #pragma unroll
            for (int n = 0; n < 4; ++n) {
                const int p = p0 + wn * 64 + n * 16 + lm;
                if (p < SS) {
                    #pragma unroll
                    for (int r = 0; r < 4; ++r) {
                        const int c = ob - 256 + r;
                        vv[((size_t)b * 256 + c) * SS + p] = f2bf(acc[m][n][r] + bv[r]);
                    }
                }
            }
        }
    }
}

// ---------------- output projection: out[b][o][p] f32 ; grid (8b, 7p, 4o) ----------------
__global__ __launch_bounds__(256) void gemm_out(const ushort* __restrict__ A,
                                                const float* __restrict__ Wg,
                                                const float* __restrict__ bias,
                                                float* __restrict__ outp) {
    __shared__ ushort As[128 * 40];
    __shared__ ushort Bs[128 * 40];
    const int tid = threadIdx.x;
    const int lane = tid & 63, wave = tid >> 6;
    const int wm = wave >> 1, wn = wave & 1;
    const int lg = lane >> 4, lm = lane & 15;
    const int b  = blockIdx.x;
    const int p0 = blockIdx.y * 128;
    const int o0 = blockIdx.z * 128;
    const int srow = tid >> 1, shalf = (tid & 1) * 16;

    const f32x4 Z4 = {0.f, 0.f, 0.f, 0.f};
    const s16x8 Z8 = {0, 0, 0, 0, 0, 0, 0, 0};
    f32x4 acc[4][4];
    #pragma unroll
    for (int m = 0; m < 4; ++m)
        #pragma unroll
        for (int n = 0; n < 4; ++n) acc[m][n] = Z4;

    for (int c0 = 0; c0 < 256; c0 += 32) {
        __syncthreads();
        {   // A: attn bf16 [p][256]
            int p = p0 + srow;
            s16x8 v0 = Z8, v1 = Z8;
            if (p < SS) {
                const ushort* src = A + ((size_t)b * SS + p) * 256 + c0 + shalf;
                v0 = *(const s16x8*)src;
                v1 = *(const s16x8*)(src + 8);
            }
            *(s16x8*)&As[srow * 40 + shalf]     = v0;
            *(s16x8*)&As[srow * 40 + shalf + 8] = v1;
        }
        {   // B: Wo f32 -> bf16
            const float* src = Wg + (size_t)(o0 + srow) * 256 + c0 + shalf;
            ushort tmp[16];
            #pragma unroll
            for (int jj = 0; jj < 4; ++jj) {
                float4 v = *(const float4*)(src + jj * 4);
                tmp[jj * 4 + 0] = f2bf(v.x); tmp[jj * 4 + 1] = f2bf(v.y);
                tmp[jj * 4 + 2] = f2bf(v.z); tmp[jj * 4 + 3] = f2bf(v.w);
            }
            *(s16x8*)&Bs[srow * 40 + shalf]     = *(s16x8*)&tmp[0];
            *(s16x8*)&Bs[srow * 40 + shalf + 8] = *(s16x8*)&tmp[8];
        }
        __syncthreads();
        s16x8 af[4], bf[4];
        #pragma unroll
        for (int m = 0; m < 4; ++m) af[m] = *(const s16x8*)&As[(wm * 64 + m * 16 + lm) * 40 + 8 * lg];
        #pragma unroll
        for (int n = 0; n < 4; ++n) bf[n] = *(const s16x8*)&Bs[(wn * 64 + n * 16 + lm) * 40 + 8 * lg];
        #pragma unroll
        for (int m = 0; m < 4; ++m)
            #pragma unroll
            for (int n = 0; n < 4; ++n)
                acc[m][n] = __builtin_amdgcn_mfma_f32_16x16x32_bf16(af[m], bf[n], acc[m][n], 0, 0, 0);
    }

    #pragma unroll
    for (int n = 0; n < 4; ++n) {
        const int o = o0 + wn * 64 + n * 16 + lm;
        const float bv = bias[o];
        #pragma unroll
        for (int m = 0; m < 4; ++m) {
            const int p = p0 + wm * 64 + m * 16 + 4 * lg;
            if (p < SS) {
                f32x4 v;
                #pragma unroll
                for (int r = 0; r < 4; ++r) v[r] = acc[m][n][r] + bv;
                *(f32x4*)&outp[((size_t)b * 512 + o) * SS + p] = v;
            }
        }
    }
}

// ---------------- fused MFMA attention ----------------
// KROW=280: row stride 140 dw == 12 (mod 32) -> 3*lm+lg covers all bank groups uniformly
// -> conflict-free b128 column reads (was 8-way at KROW=264).
#define KROW 280
#define VROW 40
#define PROW 40

__global__ __launch_bounds__(256, 3) void attn_mfma(const ushort* __restrict__ qt,
                                                    const ushort* __restrict__ kt,
                                                    const ushort* __restrict__ vv,
                                                    ushort* __restrict__ pb,
                                                    ushort* __restrict__ p4) {
    __shared__ ushort ks[32 * KROW];          // 17920 B
    __shared__ ushort vs[256 * VROW];         // 20480 B
    __shared__ ushort pls[4 * 2 * 16 * PROW]; // 10240 B
    const int tid  = threadIdx.x;
    const int lane = tid & 63;
    const int wave = tid >> 6;
    const int b     = blockIdx.x;             // grid (8,65): linear%8 = b -> XCD = b
    const int stile = blockIdx.y / 5;
    const int ts    = blockIdx.y % 5;
    int strip = stile * 4 + wave;
    const bool valid = (strip < 49);
    if (!valid) strip = 48;
    const int s0 = strip * 16;

    const int lg = lane >> 4, lm = lane & 15;
    const s16x8 Z8 = {0, 0, 0, 0, 0, 0, 0, 0};
    const f32x4 Z4 = {0.f, 0.f, 0.f, 0.f};

    s16x8 qf[8];
    const ushort* qbase = qt + ((size_t)b * SS + s0 + lm) * 256 + 8 * lg;
    #pragma unroll
    for (int n = 0; n < 8; ++n) qf[n] = *(const s16x8*)(qbase + n * 32);

    f32x4 oacc[8][2];
    #pragma unroll
    for (int n = 0; n < 8; ++n) { oacc[n][0] = Z4; oacc[n][1] = Z4; }

    const ushort* ktb = kt + (size_t)b * SS * 256;
    const ushort* vb  = vv + (size_t)b * 256 * SS;
    ushort* pbase = pls + wave * (2 * 16 * PROW);

    for (int ti = ts * 5; ti < ts * 5 + 5; ++ti) {
        const int t0 = ti * 32;
        __syncthreads();
        {   // K tile [32 t][256 c]
            const int row = tid >> 3, ce = (tid & 7) * 32;
            const int t = t0 + row;
            const ushort* src = ktb + (size_t)t * 256 + ce;
            #pragma unroll
            for (int j = 0; j < 4; ++j) {
                s16x8 v = (t < SS) ? *(const s16x8*)(src + 8 * j) : Z8;
                *(s16x8*)&ks[row * KROW + ce + 8 * j] = v;
            }
        }
        {   // V tile [256 c][32 t]
            const ushort* src = vb + (size_t)tid * SS + t0;
            #pragma unroll
            for (int j = 0; j < 4; ++j) {
                s16x8 v = (t0 + 8 * j < SS) ? *(const s16x8*)(src + 8 * j) : Z8;
                *(s16x8*)&vs[tid * VROW + 8 * j] = v;
            }
        }
        __syncthreads();

        // S^T = mfma(K, Q) + head softmax (max-free exp2; q pre-scaled by log2e/sqrt(dk))
        unsigned pku[2][8][2];
        #pragma unroll
        for (int h = 0; h < 2; ++h) {
            f32x4 lacc[8];
            #pragma unroll
            for (int n = 0; n < 8; ++n) {
                s16x8 ak = *(const s16x8*)&ks[(h * 16 + lm) * KROW + n * 32 + 8 * lg];
                lacc[n] = __builtin_amdgcn_mfma_f32_16x16x32_bf16(ak, qf[n], Z4, 0, 0, 0);
            }
            #pragma unroll
            for (int r = 0; r < 4; ++r) {
                float e[8]; float sum = 0.f;
                #pragma unroll
                for (int n = 0; n < 8; ++n) { e[n] = exp2f(lacc[n][r]); sum += e[n]; }
                float inv;
                asm("v_rcp_f32 %0, %1" : "=v"(inv) : "v"(sum));
                #pragma unroll
                for (int n = 0; n < 8; ++n) lacc[n][r] = e[n] * inv;
            }
            #pragma unroll
            for (int n = 0; n < 8; ++n) {
                pku[h][n][0] = cvt_pk_bf16(lacc[n][0], lacc[n][1]);
                pku[h][n][1] = cvt_pk_bf16(lacc[n][2], lacc[n][3]);
            }
        }

        // PV via tiny wave-private ping-pong LDS bounce
        #pragma unroll
        for (int n = 0; n < 8; ++n) {
            ushort* pw = pbase + (n & 1) * (16 * PROW);
            uint2 w0; w0.x = pku[0][n][0]; w0.y = pku[0][n][1];
            *(uint2*)&pw[lm * PROW + 4 * lg] = w0;
            uint2 w1; w1.x = pku[1][n][0]; w1.y = pku[1][n][1];
            *(uint2*)&pw[lm * PROW + 16 + 4 * lg] = w1;
            s16x8 pbf = *(const s16x8*)&pw[lm * PROW + 8 * lg];
            #pragma unroll
            for (int dh = 0; dh < 2; ++dh) {
                s16x8 va = *(const s16x8*)&vs[(n * 32 + dh * 16 + lm) * VROW + 8 * lg];
                oacc[n][dh] = __builtin_amdgcn_mfma_f32_16x16x32_bf16(va, pbf, oacc[n][dh], 0, 0, 0);
            }
        }
    }

    if (valid) {
        ushort* part = (ts < 4) ? (pb + (size_t)ts * NQE) : p4;
        // O^T: s = lm, d = dh*16 + 4lg + r -> f = lm*32 + dh*16 + 4lg + r (r contiguous)
        const size_t base = (size_t)b * 200704 + (size_t)s0 * 32 + lm * 32 + 4 * lg;
        #pragma unroll
        for (int n = 0; n < 8; ++n) {
            #pragma unroll
            for (int dh = 0; dh < 2; ++dh) {
                uint2 w;
                w.x = cvt_pk_bf16(oacc[n][dh][0], oacc[n][dh][1]);
                w.y = cvt_pk_bf16(oacc[n][dh][2], oacc[n][dh][3]);
                *(uint2*)&part[base + n * 25088 + dh * 16] = w;
            }
        }
    }
}

// ---------------- sum 5 partials [b][c2][p] + transpose -> sumb[b][p][256] ----------------
__global__ __launch_bounds__(256) void sum5t(const ushort* __restrict__ a0,
                                             const ushort* __restrict__ a1,
                                             const ushort* __restrict__ a2,
                                             const ushort* __restrict__ a3,
                                             const ushort* __restrict__ a4,
                                             ushort* __restrict__ outb) {
    __shared__ ushort Ts[64][72];
    const int tid = threadIdx.x;
    const int p0 = blockIdx.x * 64, c0 = blockIdx.y * 64, b = blockIdx.z;
    const int cr = tid >> 2, ch = (tid & 3) * 16;
    if (p0 + ch < SS) {
        const size_t off = ((size_t)b * 256 + c0 + cr) * SS + p0 + ch;
        #pragma unroll
        for (int jj = 0; jj < 2; ++jj) {
            s16x8 v0 = *(const s16x8*)(a0 + off + 8 * jj);
            s16x8 v1 = *(const s16x8*)(a1 + off + 8 * jj);
            s16x8 v2 = *(const s16x8*)(a2 + off + 8 * jj);
            s16x8 v3 = *(const s16x8*)(a3 + off + 8 * jj);
            s16x8 v4 = *(const s16x8*)(a4 + off + 8 * jj);
            #pragma unroll
            for (int j = 0; j < 8; ++j) {
                float s = bf2f((ushort)v0[j]) + bf2f((ushort)v1[j]) + bf2f((ushort)v2[j])
                        + bf2f((ushort)v3[j]) + bf2f((ushort)v4[j]);
                Ts[ch + jj * 8 + j][cr] = f2bf(s);
            }
        }
    } else {
        #pragma unroll
        for (int j = 0; j < 16; ++j) Ts[ch + j][cr] = 0;
    }
    __syncthreads();
    const int pr = tid >> 2, cc = (tid & 3) * 16;
    if (p0 + pr < SS) {
        ushort* dst = outb + ((size_t)b * SS + p0 + pr) * 256 + c0 + cc;
        *(s16x8*)dst       = *(const s16x8*)&Ts[pr][cc];
        *(s16x8*)(dst + 8) = *(const s16x8*)&Ts[pr][cc + 8];
    }
}

extern "C" void kernel_launch(void* const* d_in, const int* in_sizes, int n_in,
                              void* d_out, int out_size, void* d_ws, size_t ws_size,
                              hipStream_t stream) {
    const float* inputs    = (const float*)d_in[0];
    const float* inputs_st = (const float*)d_in[1];
    const float* Wq        = (const float*)d_in[2];
    const float* bq        = (const float*)d_in[3];
    const float* Wkv       = (const float*)d_in[4];
    const float* bkv       = (const float*)d_in[5];
    const float* Wo        = (const float*)d_in[6];
    const float* bo        = (const float*)d_in[7];
    float* out = (float*)d_out;

    ushort* W     = (ushort*)d_ws;
    ushort* xt_q  = W;                      // slots 0-1 (later partials 0,1)
    ushort* xt_kv = W + 2 * (size_t)NQE;    // slots 2-3 (later partials 2,3)
    ushort* qt    = W + 4 * (size_t)NQE;    // slot 4 (later summed attn)
    ushort* kt    = W + 5 * (size_t)NQE;
    ushort* vv    = W + 6 * (size_t)NQE;
    ushort* p4    = W + 7 * (size_t)NQE;
    ushort* sumb  = qt;

    const float qscale = (float)(1.4426950408889634 / 5.656854249492380195); // log2(e)/sqrt(32)

    transpose_cvt2<<<dim3(13, 8, 16), dim3(256), 0, stream>>>(inputs, inputs_st, xt_q, xt_kv);
    gemm_qkv<<<dim3(336), dim3(256), 0, stream>>>(xt_q, xt_kv, Wq, bq, Wkv, bkv, qt, kt, vv, qscale);
    attn_mfma<<<dim3(8, 65), dim3(256), 0, stream>>>(qt, kt, vv, W, p4);
    sum5t<<<dim3(13, 4, 8), dim3(256), 0, stream>>>(W, W + (size_t)NQE, W + 2 * (size_t)NQE,
                                                    W + 3 * (size_t)NQE, p4, sumb);
    gemm_out<<<dim3(8, 7, 4), dim3(256), 0, stream>>>(sumb, Wo, bo, out);
}